// Round 4
// baseline (510.015 us; speedup 1.0000x reference)
//
#include <hip/hip_runtime.h>
#include <hip/hip_bf16.h>
#include <math.h>

#define B_ROWS 8192
#define D_INK  1024
#define D_H    512
#define N_E    8
#define OUT_D  1024
#define LN_EPS 1e-5f
#define GAP_TAU 3e-4f

typedef _Float16 f16x8 __attribute__((ext_vector_type(8)));
typedef _Float16 f16x4v __attribute__((ext_vector_type(4)));
typedef float    f32x4  __attribute__((ext_vector_type(4)));

__device__ __forceinline__ float gelu_exact(float x) {
  return 0.5f * x * (1.0f + erff(x * 0.707106781186547524f));
}
__device__ __forceinline__ float clamp_diag(float v) {
  return fminf(fmaxf(v, -1e15f), 1e15f);
}

// ---- x [8192][1024] fp32 -> fp16 hi + fp16 lo (residual) ----
__global__ __launch_bounds__(256) void convert_x_kernel(
    const float4* __restrict__ x4, f16x4v* __restrict__ hi4,
    f16x4v* __restrict__ lo4) {
  int i = blockIdx.x * 256 + threadIdx.x;  // grid covers N/4 exactly
  float4 v = x4[i];
  f16x4v h, l;
  h[0] = (_Float16)v.x; l[0] = (_Float16)(v.x - (float)h[0]);
  h[1] = (_Float16)v.y; l[1] = (_Float16)(v.y - (float)h[1]);
  h[2] = (_Float16)v.z; l[2] = (_Float16)(v.z - (float)h[2]);
  h[3] = (_Float16)v.w; l[3] = (_Float16)(v.w - (float)h[3]);
  hi4[i] = h; lo4[i] = l;
}

// ---- transpose fp32 [R][C] -> fp16 [C][R] (hi, optional lo), z-batched ----
__global__ void transpose_split_kernel(const float* __restrict__ src,
                                       _Float16* __restrict__ hi,
                                       _Float16* __restrict__ lo,
                                       int R, int C) {
  __shared__ float tile[32][33];
  long base = (long)blockIdx.z * R * C;
  int c0 = blockIdx.x * 32, r0 = blockIdx.y * 32;
  int tx = threadIdx.x, ty = threadIdx.y;
#pragma unroll
  for (int i = ty; i < 32; i += 8)
    tile[i][tx] = src[base + (long)(r0 + i) * C + (c0 + tx)];
  __syncthreads();
#pragma unroll
  for (int i = ty; i < 32; i += 8) {
    float v = tile[tx][i];
    _Float16 h = (_Float16)v;
    long o = base + (long)(c0 + i) * R + (r0 + tx);
    hi[o] = h;
    if (lo) lo[o] = (_Float16)(v - (float)h);
  }
}

// ---- gate GEMM, 3-term fp16 split: g = gelu(x@W1 + b1) fp32 out ----
__global__ __launch_bounds__(256) void gate_gemm3_kernel(
    const _Float16* __restrict__ xh, const _Float16* __restrict__ xl,
    const _Float16* __restrict__ wh, const _Float16* __restrict__ wl,
    const float* __restrict__ b1, float* __restrict__ g) {
  __shared__ __align__(16) unsigned short Ah[128 * 64];
  __shared__ __align__(16) unsigned short Al[128 * 64];
  __shared__ __align__(16) unsigned short Bh[128 * 64];
  __shared__ __align__(16) unsigned short Bl[128 * 64];
  int tid = threadIdx.x, lane = tid & 63, wave = tid >> 6;
  int wm = wave >> 1, wn = wave & 1;
  int n0 = blockIdx.x * 128, m0 = blockIdx.y * 128;

  const char* pah[4]; const char* pal[4];
  const char* pbh[4]; const char* pbl[4];
#pragma unroll
  for (int i = 0; i < 4; ++i) {
    int f = i * 256 + tid;
    int rowt = f >> 3, seg = f & 7;
    long ao = (long)(m0 + rowt) * (D_INK * 2) + seg * 16;
    long bo = (long)(n0 + rowt) * (D_INK * 2) + seg * 16;
    pah[i] = (const char*)xh + ao; pal[i] = (const char*)xl + ao;
    pbh[i] = (const char*)wh + bo; pbl[i] = (const char*)wl + bo;
  }
  f32x4 acc[4][4];
#pragma unroll
  for (int mi = 0; mi < 4; ++mi)
#pragma unroll
    for (int ni = 0; ni < 4; ++ni) acc[mi][ni] = (f32x4){0.f, 0.f, 0.f, 0.f};

  for (int k0 = 0; k0 < D_INK; k0 += 64) {
    f16x8 vah[4], val[4], vbh[4], vbl[4];
#pragma unroll
    for (int i = 0; i < 4; ++i) {
      vah[i] = *(const f16x8*)(pah[i] + (long)k0 * 2);
      val[i] = *(const f16x8*)(pal[i] + (long)k0 * 2);
      vbh[i] = *(const f16x8*)(pbh[i] + (long)k0 * 2);
      vbl[i] = *(const f16x8*)(pbl[i] + (long)k0 * 2);
    }
    __syncthreads();
#pragma unroll
    for (int i = 0; i < 4; ++i) {
      *(f16x8*)((char*)Ah + (i * 256 + tid) * 16) = vah[i];
      *(f16x8*)((char*)Al + (i * 256 + tid) * 16) = val[i];
      *(f16x8*)((char*)Bh + (i * 256 + tid) * 16) = vbh[i];
      *(f16x8*)((char*)Bl + (i * 256 + tid) * 16) = vbl[i];
    }
    __syncthreads();
#pragma unroll
    for (int ks = 0; ks < 2; ++ks) {
      int ko = (ks * 32 + ((lane >> 4) << 3)) * 2;
      f16x8 ah[4], al[4], bh[4], bl[4];
#pragma unroll
      for (int mi = 0; mi < 4; ++mi) {
        int ro = (wm * 64 + mi * 16 + (lane & 15)) * 128 + ko;
        ah[mi] = *(const f16x8*)((const char*)Ah + ro);
        al[mi] = *(const f16x8*)((const char*)Al + ro);
      }
#pragma unroll
      for (int ni = 0; ni < 4; ++ni) {
        int ro = (wn * 64 + ni * 16 + (lane & 15)) * 128 + ko;
        bh[ni] = *(const f16x8*)((const char*)Bh + ro);
        bl[ni] = *(const f16x8*)((const char*)Bl + ro);
      }
#pragma unroll
      for (int mi = 0; mi < 4; ++mi)
#pragma unroll
        for (int ni = 0; ni < 4; ++ni) {
          acc[mi][ni] = __builtin_amdgcn_mfma_f32_16x16x32_f16(ah[mi], bh[ni], acc[mi][ni], 0, 0, 0);
          acc[mi][ni] = __builtin_amdgcn_mfma_f32_16x16x32_f16(ah[mi], bl[ni], acc[mi][ni], 0, 0, 0);
          acc[mi][ni] = __builtin_amdgcn_mfma_f32_16x16x32_f16(al[mi], bh[ni], acc[mi][ni], 0, 0, 0);
        }
    }
  }
  int quad = lane >> 4, cl = lane & 15;
#pragma unroll
  for (int mi = 0; mi < 4; ++mi)
#pragma unroll
    for (int r = 0; r < 4; ++r) {
      int row = m0 + wm * 64 + mi * 16 + quad * 4 + r;
#pragma unroll
      for (int ni = 0; ni < 4; ++ni) {
        int col = n0 + wn * 64 + ni * 16 + cl;
        float v = clamp_diag(acc[mi][ni][r] + b1[col]);
        g[(long)row * D_H + col] = gelu_exact(v);
      }
    }
}

// ---- Phase A: scores (fp32) + flag close 2nd/3rd gaps. One wave per row ----
__global__ __launch_bounds__(256) void score_kernel(
    const float* __restrict__ g, const float* __restrict__ w2,
    const float* __restrict__ b2, float* __restrict__ scores,
    int* __restrict__ nflag, int* __restrict__ worklist) {
  int tid = threadIdx.x, lane = tid & 63, wave = tid >> 6;
  int b = blockIdx.x * 4 + wave;
  const float* grow = g + (long)b * D_H + lane * 8;
  float4 g0 = *(const float4*)grow;
  float4 g1 = *(const float4*)(grow + 4);
  float gv[8] = {g0.x, g0.y, g0.z, g0.w, g1.x, g1.y, g1.z, g1.w};
  float acc[8];
#pragma unroll
  for (int e = 0; e < 8; ++e) acc[e] = 0.f;
#pragma unroll
  for (int j = 0; j < 8; ++j) {
    const float* wrow = w2 + (lane * 8 + j) * N_E;
#pragma unroll
    for (int e = 0; e < 8; ++e) acc[e] += gv[j] * wrow[e];
  }
#pragma unroll
  for (int off = 32; off >= 1; off >>= 1)
#pragma unroll
    for (int e = 0; e < 8; ++e) acc[e] += __shfl_xor(acc[e], off, 64);
  if (lane == 0) {
    float s[8];
#pragma unroll
    for (int e = 0; e < 8; ++e) { s[e] = acc[e] + b2[e]; scores[b * N_E + e] = s[e]; }
    int i0 = 0;
#pragma unroll
    for (int e = 1; e < 8; ++e) if (s[e] > s[i0]) i0 = e;
    int i1 = (i0 == 0) ? 1 : 0;
#pragma unroll
    for (int e = 0; e < 8; ++e) if (e != i0 && s[e] > s[i1]) i1 = e;
    float s2 = -3e38f;
#pragma unroll
    for (int e = 0; e < 8; ++e) if (e != i0 && e != i1 && s[e] > s2) s2 = s[e];
    if (s[i1] - s2 < GAP_TAU) {
      int idx = atomicAdd(nflag, 1);
      worklist[idx] = b;
    }
  }
}

// ---- Phase B: fp64 recompute of scores for flagged rows ----
__global__ __launch_bounds__(256) void fixup_kernel(
    const float* __restrict__ x, const float* __restrict__ w1,
    const float* __restrict__ b1, const float* __restrict__ w2,
    const float* __restrict__ b2, const int* __restrict__ nflag,
    const int* __restrict__ worklist, float* __restrict__ scores) {
  __shared__ double gbuf[D_H];
  int n = *nflag;
  int j = threadIdx.x;
  for (int w = blockIdx.x; w < n; w += gridDim.x) {
    int row = worklist[w];
#pragma unroll
    for (int half = 0; half < 2; ++half) {
      int col = j + half * 256;
      double a = 0.0;
      for (int k = 0; k < D_INK; ++k)
        a += (double)x[(long)row * D_INK + k] * (double)w1[(long)k * D_H + col];
      a += (double)b1[col];
      gbuf[col] = 0.5 * a * (1.0 + erf(a * 0.70710678118654752440));
    }
    __syncthreads();
    if (j < N_E) {
      double s = 0.0;
      for (int q = 0; q < D_H; ++q) s += gbuf[q] * (double)w2[q * N_E + j];
      s += (double)b2[j];
      scores[row * N_E + j] = (float)s;
    }
    __syncthreads();
  }
}

// ---- Phase C: top-2 selection + softmax + bucket scatter (thread/row) ----
__global__ __launch_bounds__(256) void select_kernel(
    const float* __restrict__ scores, int* __restrict__ counts,
    int* __restrict__ bucket, float* __restrict__ pair_w,
    int* __restrict__ pair_e) {
  int b = blockIdx.x * 256 + threadIdx.x;
  float s[8];
#pragma unroll
  for (int e = 0; e < 8; ++e) s[e] = scores[b * N_E + e];
  int i0 = 0;
#pragma unroll
  for (int e = 1; e < 8; ++e) if (s[e] > s[i0]) i0 = e;
  int i1 = (i0 == 0) ? 1 : 0;
#pragma unroll
  for (int e = 0; e < 8; ++e) if (e != i0 && s[e] > s[i1]) i1 = e;
  float z = expf(s[i1] - s[i0]);  // <= 1
  float inv = 1.0f / (1.0f + z);
  int p0 = 2 * b, p1 = 2 * b + 1;
  pair_e[p0] = i0; pair_w[p0] = inv;
  pair_e[p1] = i1; pair_w[p1] = z * inv;
  int q0 = atomicAdd(&counts[i0], 1); bucket[i0 * B_ROWS + q0] = p0;
  int q1 = atomicAdd(&counts[i1], 1); bucket[i1 * B_ROWS + q1] = p1;
}

// ---- grouped expert GEMM (fp16): h[pair] = x[row] @ We[e], bf16 out ----
__global__ __launch_bounds__(256) void expert_gemm_kernel(
    const _Float16* __restrict__ xh, const _Float16* __restrict__ wet,
    const int* __restrict__ counts, const int* __restrict__ bucket,
    __bf16* __restrict__ h) {
  int nt = blockIdx.x, mt = blockIdx.y, e = blockIdx.z;
  int cnt = counts[e];
  if (mt * 128 >= cnt) return;
  __shared__ __align__(16) unsigned short As[128 * 64];
  __shared__ __align__(16) unsigned short Bs[128 * 64];
  __shared__ int dest_s[128];
  int tid = threadIdx.x, lane = tid & 63, wave = tid >> 6;
  int wm = wave >> 1, wn = wave & 1;
  int n0 = nt * 128;
  if (tid < 128) {
    int idx = mt * 128 + tid;
    dest_s[tid] = (idx < cnt) ? bucket[e * B_ROWS + idx] : 0;
  }
  __syncthreads();
  const char* xb = (const char*)xh;
  const char* wb = (const char*)wet + (long)e * (D_INK * OUT_D * 2);
  const char* aptr[4];
  const char* bptr[4];
#pragma unroll
  for (int i = 0; i < 4; ++i) {
    int f = i * 256 + tid;
    int rowt = f >> 3, seg = f & 7;
    int rowid = dest_s[rowt] >> 1;
    aptr[i] = xb + (long)rowid * (D_INK * 2) + seg * 16;
    bptr[i] = wb + (long)(n0 + rowt) * (D_INK * 2) + seg * 16;
  }
  f32x4 acc[4][4];
#pragma unroll
  for (int mi = 0; mi < 4; ++mi)
#pragma unroll
    for (int ni = 0; ni < 4; ++ni) acc[mi][ni] = (f32x4){0.f, 0.f, 0.f, 0.f};

  for (int k0 = 0; k0 < D_INK; k0 += 64) {
    f16x8 av[4], bv[4];
#pragma unroll
    for (int i = 0; i < 4; ++i) av[i] = *(const f16x8*)(aptr[i] + (long)k0 * 2);
#pragma unroll
    for (int i = 0; i < 4; ++i) bv[i] = *(const f16x8*)(bptr[i] + (long)k0 * 2);
    __syncthreads();
#pragma unroll
    for (int i = 0; i < 4; ++i)
      *(f16x8*)((char*)As + (i * 256 + tid) * 16) = av[i];
#pragma unroll
    for (int i = 0; i < 4; ++i)
      *(f16x8*)((char*)Bs + (i * 256 + tid) * 16) = bv[i];
    __syncthreads();
#pragma unroll
    for (int ks = 0; ks < 2; ++ks) {
      int ko = (ks * 32 + ((lane >> 4) << 3)) * 2;
      f16x8 af[4], bfr[4];
#pragma unroll
      for (int mi = 0; mi < 4; ++mi)
        af[mi] = *(const f16x8*)((const char*)As + (wm * 64 + mi * 16 + (lane & 15)) * 128 + ko);
#pragma unroll
      for (int ni = 0; ni < 4; ++ni)
        bfr[ni] = *(const f16x8*)((const char*)Bs + (wn * 64 + ni * 16 + (lane & 15)) * 128 + ko);
#pragma unroll
      for (int mi = 0; mi < 4; ++mi)
#pragma unroll
        for (int ni = 0; ni < 4; ++ni)
          acc[mi][ni] = __builtin_amdgcn_mfma_f32_16x16x32_f16(af[mi], bfr[ni], acc[mi][ni], 0, 0, 0);
    }
  }
  int quad = lane >> 4, cl = lane & 15;
#pragma unroll
  for (int mi = 0; mi < 4; ++mi)
#pragma unroll
    for (int r = 0; r < 4; ++r) {
      int row128 = wm * 64 + mi * 16 + quad * 4 + r;
      if (mt * 128 + row128 < cnt) {
        long dest = dest_s[row128];
        __bf16* hp = h + dest * OUT_D + n0 + wn * 64 + cl;
#pragma unroll
        for (int ni = 0; ni < 4; ++ni)
          hp[ni * 16] = (__bf16)clamp_diag(acc[mi][ni][r]);
      }
    }
}

// ---- LN(+be) -> GELU -> weighted combine -> fp32 out (block per row) ----
__global__ __launch_bounds__(256) void ln_combine_kernel(
    const __bf16* __restrict__ h, const float* __restrict__ pair_w,
    const int* __restrict__ pair_e, const float* __restrict__ be,
    const float* __restrict__ ln_g, const float* __restrict__ ln_b,
    float* __restrict__ out) {
  int b = blockIdx.x, tid = threadIdx.x;
  int lane = tid & 63, wave = tid >> 6;
  __shared__ float red[4][4];
  float hv[2][4];
  float stats[4];
  int ei[2]; float wi[2];
#pragma unroll
  for (int k = 0; k < 2; ++k) {
    int p = 2 * b + k;
    ei[k] = pair_e[p]; wi[k] = pair_w[p];
    const __bf16* hp = h + (long)p * OUT_D;
    const float* bep = be + ei[k] * OUT_D;
    float s = 0.f, sq = 0.f;
#pragma unroll
    for (int j = 0; j < 4; ++j) {
      int col = tid + j * 256;
      float v = (float)hp[col] + bep[col];
      hv[k][j] = v; s += v; sq += v * v;
    }
    stats[2 * k] = s; stats[2 * k + 1] = sq;
  }
#pragma unroll
  for (int off = 32; off >= 1; off >>= 1)
#pragma unroll
    for (int i = 0; i < 4; ++i) stats[i] += __shfl_xor(stats[i], off, 64);
  if (lane == 0) {
#pragma unroll
    for (int i = 0; i < 4; ++i) red[wave][i] = stats[i];
  }
  __syncthreads();
  float tot[4] = {0.f, 0.f, 0.f, 0.f};
#pragma unroll
  for (int w = 0; w < 4; ++w)
#pragma unroll
    for (int i = 0; i < 4; ++i) tot[i] += red[w][i];
  float outv[4] = {0.f, 0.f, 0.f, 0.f};
#pragma unroll
  for (int k = 0; k < 2; ++k) {
    float mean = tot[2 * k] * (1.0f / OUT_D);
    float var = tot[2 * k + 1] * (1.0f / OUT_D) - mean * mean;
    float rstd = rsqrtf(fmaxf(var, 0.f) + LN_EPS);
    const float* gp = ln_g + ei[k] * OUT_D;
    const float* bp = ln_b + ei[k] * OUT_D;
#pragma unroll
    for (int j = 0; j < 4; ++j) {
      int col = tid + j * 256;
      float t = (hv[k][j] - mean) * rstd * gp[col] + bp[col];
      outv[j] += wi[k] * gelu_exact(t);
    }
  }
#pragma unroll
  for (int j = 0; j < 4; ++j)
    out[(long)b * OUT_D + tid + j * 256] = outv[j];
}

extern "C" void kernel_launch(void* const* d_in, const int* in_sizes, int n_in,
                              void* d_out, int out_size, void* d_ws, size_t ws_size,
                              hipStream_t stream) {
  const float* x       = (const float*)d_in[0];
  const float* gate_w1 = (const float*)d_in[1];
  const float* gate_b1 = (const float*)d_in[2];
  const float* gate_w2 = (const float*)d_in[3];
  const float* gate_b2 = (const float*)d_in[4];
  const float* We      = (const float*)d_in[5];
  const float* be      = (const float*)d_in[6];
  const float* ln_g    = (const float*)d_in[7];
  const float* ln_b    = (const float*)d_in[8];
  float* out = (float*)d_out;  // reference output dtype is float32

  char* ws = (char*)d_ws;
  size_t off = 0;
  _Float16* x16h = (_Float16*)(ws + off); off += (size_t)B_ROWS * D_INK * 2;   // 16 MB
  _Float16* x16l = (_Float16*)(ws + off); off += (size_t)B_ROWS * D_INK * 2;   // 16 MB
  _Float16* w1th = (_Float16*)(ws + off); off += (size_t)D_H * D_INK * 2;      // 1 MB
  _Float16* w1tl = (_Float16*)(ws + off); off += (size_t)D_H * D_INK * 2;      // 1 MB
  _Float16* wet  = (_Float16*)(ws + off); off += (size_t)N_E * D_INK * OUT_D * 2; // 16 MB
  float* g       = (float*)(ws + off); off += (size_t)B_ROWS * D_H * 4;        // 16 MB
  float* scores  = (float*)(ws + off); off += (size_t)B_ROWS * N_E * 4;        // 256 KB
  int* counts    = (int*)(ws + off);   off += 64;  // counts[8] + nflag
  int* nflag     = counts + 8;
  int* worklist  = (int*)(ws + off);   off += (size_t)B_ROWS * 4;              // 32 KB
  int* bucket    = (int*)(ws + off);   off += (size_t)N_E * B_ROWS * 4;        // 256 KB
  float* pair_w  = (float*)(ws + off); off += (size_t)2 * B_ROWS * 4;
  int* pair_e    = (int*)(ws + off);   off += (size_t)2 * B_ROWS * 4;
  __bf16* h      = (__bf16*)(ws + off); off += (size_t)2 * B_ROWS * OUT_D * 2; // 32 MB

  hipMemsetAsync(counts, 0, 64, stream);
  convert_x_kernel<<<B_ROWS * D_INK / 4 / 256, 256, 0, stream>>>(
      (const float4*)x, (f16x4v*)x16h, (f16x4v*)x16l);
  transpose_split_kernel<<<dim3(D_H / 32, D_INK / 32, 1), dim3(32, 8), 0, stream>>>(
      gate_w1, w1th, w1tl, D_INK, D_H);
  transpose_split_kernel<<<dim3(OUT_D / 32, D_INK / 32, N_E), dim3(32, 8), 0, stream>>>(
      We, wet, (_Float16*)nullptr, D_INK, OUT_D);
  gate_gemm3_kernel<<<dim3(D_H / 128, B_ROWS / 128), 256, 0, stream>>>(
      x16h, x16l, w1th, w1tl, gate_b1, g);
  score_kernel<<<B_ROWS / 4, 256, 0, stream>>>(
      g, gate_w2, gate_b2, scores, nflag, worklist);
  fixup_kernel<<<64, 256, 0, stream>>>(
      x, gate_w1, gate_b1, gate_w2, gate_b2, nflag, worklist, scores);
  select_kernel<<<B_ROWS / 256, 256, 0, stream>>>(
      scores, counts, bucket, pair_w, pair_e);
  expert_gemm_kernel<<<dim3(OUT_D / 128, B_ROWS / 128, N_E), 256, 0, stream>>>(
      x16h, wet, counts, bucket, h);
  ln_combine_kernel<<<B_ROWS, 256, 0, stream>>>(
      h, pair_w, pair_e, be, ln_g, ln_b, out);
}

// Round 5
// 448.991 us; speedup vs baseline: 1.1359x; 1.1359x over previous
//
#include <hip/hip_runtime.h>
#include <hip/hip_bf16.h>
#include <math.h>

#define B_ROWS 8192
#define D_INK  1024
#define D_H    512
#define N_E    8
#define OUT_D  1024
#define LN_EPS 1e-5f
#define GAP_TAU 3e-3f

typedef _Float16 f16x8 __attribute__((ext_vector_type(8)));
typedef _Float16 f16x4v __attribute__((ext_vector_type(4)));
typedef float    f32x4  __attribute__((ext_vector_type(4)));

__device__ __forceinline__ float gelu_exact(float x) {
  return 0.5f * x * (1.0f + erff(x * 0.707106781186547524f));
}
__device__ __forceinline__ float clamp_diag(float v) {
  return fminf(fmaxf(v, -1e15f), 1e15f);
}

// ---- x [8192][1024] fp32 -> fp16 ----
__global__ __launch_bounds__(256) void convert_x_kernel(
    const float4* __restrict__ x4, f16x4v* __restrict__ hi4) {
  int i = blockIdx.x * 256 + threadIdx.x;  // grid covers N/4 exactly
  float4 v = x4[i];
  f16x4v h;
  h[0] = (_Float16)v.x; h[1] = (_Float16)v.y;
  h[2] = (_Float16)v.z; h[3] = (_Float16)v.w;
  hi4[i] = h;
}

// ---- transpose fp32 [R][C] -> fp16 [C][R], z-batched ----
__global__ void transpose_split_kernel(const float* __restrict__ src,
                                       _Float16* __restrict__ hi,
                                       int R, int C) {
  __shared__ float tile[32][33];
  long base = (long)blockIdx.z * R * C;
  int c0 = blockIdx.x * 32, r0 = blockIdx.y * 32;
  int tx = threadIdx.x, ty = threadIdx.y;
#pragma unroll
  for (int i = ty; i < 32; i += 8)
    tile[i][tx] = src[base + (long)(r0 + i) * C + (c0 + tx)];
  __syncthreads();
#pragma unroll
  for (int i = ty; i < 32; i += 8)
    hi[base + (long)(c0 + i) * R + (r0 + tx)] = (_Float16)tile[tx][i];
}

// ---- gate GEMM, fp16 1-term: g = gelu(x@W1 + b1) fp32 out ----
// (score precision protected by GAP_TAU flag + fp64 fixup)
__global__ __launch_bounds__(256) void gate_gemm_kernel(
    const _Float16* __restrict__ xh, const _Float16* __restrict__ wh,
    const float* __restrict__ b1, float* __restrict__ g) {
  __shared__ __align__(16) unsigned short Ah[128 * 64];
  __shared__ __align__(16) unsigned short Bh[128 * 64];
  int tid = threadIdx.x, lane = tid & 63, wave = tid >> 6;
  int wm = wave >> 1, wn = wave & 1;
  int n0 = blockIdx.x * 128, m0 = blockIdx.y * 128;

  const char* pah[4]; const char* pbh[4];
#pragma unroll
  for (int i = 0; i < 4; ++i) {
    int f = i * 256 + tid;
    int rowt = f >> 3, seg = f & 7;
    pah[i] = (const char*)xh + (long)(m0 + rowt) * (D_INK * 2) + seg * 16;
    pbh[i] = (const char*)wh + (long)(n0 + rowt) * (D_INK * 2) + seg * 16;
  }
  f32x4 acc[4][4];
#pragma unroll
  for (int mi = 0; mi < 4; ++mi)
#pragma unroll
    for (int ni = 0; ni < 4; ++ni) acc[mi][ni] = (f32x4){0.f, 0.f, 0.f, 0.f};

  for (int k0 = 0; k0 < D_INK; k0 += 64) {
    f16x8 vah[4], vbh[4];
#pragma unroll
    for (int i = 0; i < 4; ++i) {
      vah[i] = *(const f16x8*)(pah[i] + (long)k0 * 2);
      vbh[i] = *(const f16x8*)(pbh[i] + (long)k0 * 2);
    }
    __syncthreads();
#pragma unroll
    for (int i = 0; i < 4; ++i) {
      *(f16x8*)((char*)Ah + (i * 256 + tid) * 16) = vah[i];
      *(f16x8*)((char*)Bh + (i * 256 + tid) * 16) = vbh[i];
    }
    __syncthreads();
#pragma unroll
    for (int ks = 0; ks < 2; ++ks) {
      int ko = (ks * 32 + ((lane >> 4) << 3)) * 2;
      f16x8 ah[4], bh[4];
#pragma unroll
      for (int mi = 0; mi < 4; ++mi)
        ah[mi] = *(const f16x8*)((const char*)Ah + (wm * 64 + mi * 16 + (lane & 15)) * 128 + ko);
#pragma unroll
      for (int ni = 0; ni < 4; ++ni)
        bh[ni] = *(const f16x8*)((const char*)Bh + (wn * 64 + ni * 16 + (lane & 15)) * 128 + ko);
#pragma unroll
      for (int mi = 0; mi < 4; ++mi)
#pragma unroll
        for (int ni = 0; ni < 4; ++ni)
          acc[mi][ni] = __builtin_amdgcn_mfma_f32_16x16x32_f16(ah[mi], bh[ni], acc[mi][ni], 0, 0, 0);
    }
  }
  int quad = lane >> 4, cl = lane & 15;
#pragma unroll
  for (int mi = 0; mi < 4; ++mi)
#pragma unroll
    for (int r = 0; r < 4; ++r) {
      int row = m0 + wm * 64 + mi * 16 + quad * 4 + r;
#pragma unroll
      for (int ni = 0; ni < 4; ++ni) {
        int col = n0 + wn * 64 + ni * 16 + cl;
        float v = clamp_diag(acc[mi][ni][r] + b1[col]);
        g[(long)row * D_H + col] = gelu_exact(v);
      }
    }
}

// ---- Phase A: scores (fp32) + flag close 2nd/3rd gaps. One wave per row ----
__global__ __launch_bounds__(256) void score_kernel(
    const float* __restrict__ g, const float* __restrict__ w2,
    const float* __restrict__ b2, float* __restrict__ scores,
    int* __restrict__ nflag, int* __restrict__ worklist) {
  int tid = threadIdx.x, lane = tid & 63, wave = tid >> 6;
  int b = blockIdx.x * 4 + wave;
  const float* grow = g + (long)b * D_H + lane * 8;
  float4 g0 = *(const float4*)grow;
  float4 g1 = *(const float4*)(grow + 4);
  float gv[8] = {g0.x, g0.y, g0.z, g0.w, g1.x, g1.y, g1.z, g1.w};
  float acc[8];
#pragma unroll
  for (int e = 0; e < 8; ++e) acc[e] = 0.f;
#pragma unroll
  for (int j = 0; j < 8; ++j) {
    const float* wrow = w2 + (lane * 8 + j) * N_E;
#pragma unroll
    for (int e = 0; e < 8; ++e) acc[e] += gv[j] * wrow[e];
  }
#pragma unroll
  for (int off = 32; off >= 1; off >>= 1)
#pragma unroll
    for (int e = 0; e < 8; ++e) acc[e] += __shfl_xor(acc[e], off, 64);
  if (lane == 0) {
    float s[8];
#pragma unroll
    for (int e = 0; e < 8; ++e) { s[e] = acc[e] + b2[e]; scores[b * N_E + e] = s[e]; }
    int i0 = 0;
#pragma unroll
    for (int e = 1; e < 8; ++e) if (s[e] > s[i0]) i0 = e;
    int i1 = (i0 == 0) ? 1 : 0;
#pragma unroll
    for (int e = 0; e < 8; ++e) if (e != i0 && s[e] > s[i1]) i1 = e;
    float s2 = -3e38f;
#pragma unroll
    for (int e = 0; e < 8; ++e) if (e != i0 && e != i1 && s[e] > s2) s2 = s[e];
    if (s[i1] - s2 < GAP_TAU) {
      int idx = atomicAdd(nflag, 1);
      worklist[idx] = b;
    }
  }
}

// ---- Phase B: fp64 recompute, 256 threads cooperating per row ----
__global__ __launch_bounds__(256) void fixup_kernel(
    const float* __restrict__ x, const float* __restrict__ w1,
    const float* __restrict__ b1, const float* __restrict__ w2,
    const float* __restrict__ b2, const int* __restrict__ nflag,
    const int* __restrict__ worklist, float* __restrict__ scores) {
  __shared__ double gbuf[D_H];
  __shared__ double part[4][64];
  __shared__ double p2[256];
  int n = *nflag;
  int tid = threadIdx.x, lane = tid & 63, wave = tid >> 6;
  for (int w = blockIdx.x; w < n; w += gridDim.x) {
    int row = worklist[w];
    const float* xr = x + (long)row * D_INK;
    // phase 1: g[col] in fp64; 8 passes of 64 cols, k split across 4 waves
#pragma unroll 1
    for (int pass = 0; pass < 8; ++pass) {
      int col = pass * 64 + lane;
      double a = 0.0;
      int kbeg = wave * 256;
      for (int k = kbeg; k < kbeg + 256; ++k)
        a += (double)xr[k] * (double)w1[(long)k * D_H + col];
      part[wave][lane] = a;
      __syncthreads();
      if (wave == 0) {
        double s = part[0][lane] + part[1][lane] + part[2][lane] + part[3][lane]
                 + (double)b1[col];
        gbuf[col] = 0.5 * s * (1.0 + erf(s * 0.70710678118654752440));
      }
      __syncthreads();
    }
    // phase 2: scores[e] = gbuf . w2[:,e] in fp64
    int e = tid & 7, seg = tid >> 3;  // 32 segments of 16
    double s = 0.0;
#pragma unroll
    for (int q = seg * 16; q < seg * 16 + 16; ++q)
      s += gbuf[q] * (double)w2[q * N_E + e];
    p2[tid] = s;
    __syncthreads();
    if (tid < N_E) {
      double t = 0.0;
      for (int i = 0; i < 32; ++i) t += p2[i * 8 + tid];
      scores[row * N_E + tid] = (float)(t + (double)b2[tid]);
    }
    __syncthreads();
  }
}

// ---- Phase C: top-2 selection + softmax + bucket scatter (thread/row) ----
__global__ __launch_bounds__(256) void select_kernel(
    const float* __restrict__ scores, int* __restrict__ counts,
    int* __restrict__ bucket, float* __restrict__ pair_w,
    int* __restrict__ pair_e) {
  int b = blockIdx.x * 256 + threadIdx.x;
  float s[8];
#pragma unroll
  for (int e = 0; e < 8; ++e) s[e] = scores[b * N_E + e];
  int i0 = 0;
#pragma unroll
  for (int e = 1; e < 8; ++e) if (s[e] > s[i0]) i0 = e;
  int i1 = (i0 == 0) ? 1 : 0;
#pragma unroll
  for (int e = 0; e < 8; ++e) if (e != i0 && s[e] > s[i1]) i1 = e;
  float z = expf(s[i1] - s[i0]);  // <= 1
  float inv = 1.0f / (1.0f + z);
  int p0 = 2 * b, p1 = 2 * b + 1;
  pair_e[p0] = i0; pair_w[p0] = inv;
  pair_e[p1] = i1; pair_w[p1] = z * inv;
  int q0 = atomicAdd(&counts[i0], 1); bucket[i0 * B_ROWS + q0] = p0;
  int q1 = atomicAdd(&counts[i1], 1); bucket[i1 * B_ROWS + q1] = p1;
}

// ---- grouped expert GEMM (fp16): h[pair] = x[row] @ We[e], bf16 out ----
__global__ __launch_bounds__(256) void expert_gemm_kernel(
    const _Float16* __restrict__ xh, const _Float16* __restrict__ wet,
    const int* __restrict__ counts, const int* __restrict__ bucket,
    __bf16* __restrict__ h) {
  int nt = blockIdx.x, mt = blockIdx.y, e = blockIdx.z;
  int cnt = counts[e];
  if (mt * 128 >= cnt) return;
  __shared__ __align__(16) unsigned short As[128 * 64];
  __shared__ __align__(16) unsigned short Bs[128 * 64];
  __shared__ int dest_s[128];
  int tid = threadIdx.x, lane = tid & 63, wave = tid >> 6;
  int wm = wave >> 1, wn = wave & 1;
  int n0 = nt * 128;
  if (tid < 128) {
    int idx = mt * 128 + tid;
    dest_s[tid] = (idx < cnt) ? bucket[e * B_ROWS + idx] : 0;
  }
  __syncthreads();
  const char* xb = (const char*)xh;
  const char* wb = (const char*)wet + (long)e * (D_INK * OUT_D * 2);
  const char* aptr[4];
  const char* bptr[4];
#pragma unroll
  for (int i = 0; i < 4; ++i) {
    int f = i * 256 + tid;
    int rowt = f >> 3, seg = f & 7;
    int rowid = dest_s[rowt] >> 1;
    aptr[i] = xb + (long)rowid * (D_INK * 2) + seg * 16;
    bptr[i] = wb + (long)(n0 + rowt) * (D_INK * 2) + seg * 16;
  }
  f32x4 acc[4][4];
#pragma unroll
  for (int mi = 0; mi < 4; ++mi)
#pragma unroll
    for (int ni = 0; ni < 4; ++ni) acc[mi][ni] = (f32x4){0.f, 0.f, 0.f, 0.f};

  for (int k0 = 0; k0 < D_INK; k0 += 64) {
    f16x8 av[4], bv[4];
#pragma unroll
    for (int i = 0; i < 4; ++i) av[i] = *(const f16x8*)(aptr[i] + (long)k0 * 2);
#pragma unroll
    for (int i = 0; i < 4; ++i) bv[i] = *(const f16x8*)(bptr[i] + (long)k0 * 2);
    __syncthreads();
#pragma unroll
    for (int i = 0; i < 4; ++i)
      *(f16x8*)((char*)As + (i * 256 + tid) * 16) = av[i];
#pragma unroll
    for (int i = 0; i < 4; ++i)
      *(f16x8*)((char*)Bs + (i * 256 + tid) * 16) = bv[i];
    __syncthreads();
#pragma unroll
    for (int ks = 0; ks < 2; ++ks) {
      int ko = (ks * 32 + ((lane >> 4) << 3)) * 2;
      f16x8 af[4], bfr[4];
#pragma unroll
      for (int mi = 0; mi < 4; ++mi)
        af[mi] = *(const f16x8*)((const char*)As + (wm * 64 + mi * 16 + (lane & 15)) * 128 + ko);
#pragma unroll
      for (int ni = 0; ni < 4; ++ni)
        bfr[ni] = *(const f16x8*)((const char*)Bs + (wn * 64 + ni * 16 + (lane & 15)) * 128 + ko);
#pragma unroll
      for (int mi = 0; mi < 4; ++mi)
#pragma unroll
        for (int ni = 0; ni < 4; ++ni)
          acc[mi][ni] = __builtin_amdgcn_mfma_f32_16x16x32_f16(af[mi], bfr[ni], acc[mi][ni], 0, 0, 0);
    }
  }
  int quad = lane >> 4, cl = lane & 15;
#pragma unroll
  for (int mi = 0; mi < 4; ++mi)
#pragma unroll
    for (int r = 0; r < 4; ++r) {
      int row128 = wm * 64 + mi * 16 + quad * 4 + r;
      if (mt * 128 + row128 < cnt) {
        long dest = dest_s[row128];
        __bf16* hp = h + dest * OUT_D + n0 + wn * 64 + cl;
#pragma unroll
        for (int ni = 0; ni < 4; ++ni)
          hp[ni * 16] = (__bf16)clamp_diag(acc[mi][ni][r]);
      }
    }
}

// ---- LN(+be) -> GELU -> weighted combine -> fp32 out (block per row) ----
__global__ __launch_bounds__(256) void ln_combine_kernel(
    const __bf16* __restrict__ h, const float* __restrict__ pair_w,
    const int* __restrict__ pair_e, const float* __restrict__ be,
    const float* __restrict__ ln_g, const float* __restrict__ ln_b,
    float* __restrict__ out) {
  int b = blockIdx.x, tid = threadIdx.x;
  int lane = tid & 63, wave = tid >> 6;
  __shared__ float red[4][4];
  float hv[2][4];
  float stats[4];
  int ei[2]; float wi[2];
#pragma unroll
  for (int k = 0; k < 2; ++k) {
    int p = 2 * b + k;
    ei[k] = pair_e[p]; wi[k] = pair_w[p];
    const __bf16* hp = h + (long)p * OUT_D;
    const float* bep = be + ei[k] * OUT_D;
    float s = 0.f, sq = 0.f;
#pragma unroll
    for (int j = 0; j < 4; ++j) {
      int col = tid + j * 256;
      float v = (float)hp[col] + bep[col];
      hv[k][j] = v; s += v; sq += v * v;
    }
    stats[2 * k] = s; stats[2 * k + 1] = sq;
  }
#pragma unroll
  for (int off = 32; off >= 1; off >>= 1)
#pragma unroll
    for (int i = 0; i < 4; ++i) stats[i] += __shfl_xor(stats[i], off, 64);
  if (lane == 0) {
#pragma unroll
    for (int i = 0; i < 4; ++i) red[wave][i] = stats[i];
  }
  __syncthreads();
  float tot[4] = {0.f, 0.f, 0.f, 0.f};
#pragma unroll
  for (int w = 0; w < 4; ++w)
#pragma unroll
    for (int i = 0; i < 4; ++i) tot[i] += red[w][i];
  float outv[4] = {0.f, 0.f, 0.f, 0.f};
#pragma unroll
  for (int k = 0; k < 2; ++k) {
    float mean = tot[2 * k] * (1.0f / OUT_D);
    float var = tot[2 * k + 1] * (1.0f / OUT_D) - mean * mean;
    float rstd = rsqrtf(fmaxf(var, 0.f) + LN_EPS);
    const float* gp = ln_g + ei[k] * OUT_D;
    const float* bp = ln_b + ei[k] * OUT_D;
#pragma unroll
    for (int j = 0; j < 4; ++j) {
      int col = tid + j * 256;
      float t = (hv[k][j] - mean) * rstd * gp[col] + bp[col];
      outv[j] += wi[k] * gelu_exact(t);
    }
  }
#pragma unroll
  for (int j = 0; j < 4; ++j)
    out[(long)b * OUT_D + tid + j * 256] = outv[j];
}

extern "C" void kernel_launch(void* const* d_in, const int* in_sizes, int n_in,
                              void* d_out, int out_size, void* d_ws, size_t ws_size,
                              hipStream_t stream) {
  const float* x       = (const float*)d_in[0];
  const float* gate_w1 = (const float*)d_in[1];
  const float* gate_b1 = (const float*)d_in[2];
  const float* gate_w2 = (const float*)d_in[3];
  const float* gate_b2 = (const float*)d_in[4];
  const float* We      = (const float*)d_in[5];
  const float* be      = (const float*)d_in[6];
  const float* ln_g    = (const float*)d_in[7];
  const float* ln_b    = (const float*)d_in[8];
  float* out = (float*)d_out;  // reference output dtype is float32

  char* ws = (char*)d_ws;
  size_t off = 0;
  _Float16* x16h = (_Float16*)(ws + off); off += (size_t)B_ROWS * D_INK * 2;   // 16 MB
  _Float16* w1th = (_Float16*)(ws + off); off += (size_t)D_H * D_INK * 2;      // 1 MB
  _Float16* wet  = (_Float16*)(ws + off); off += (size_t)N_E * D_INK * OUT_D * 2; // 16 MB
  float* g       = (float*)(ws + off); off += (size_t)B_ROWS * D_H * 4;        // 16 MB
  float* scores  = (float*)(ws + off); off += (size_t)B_ROWS * N_E * 4;        // 256 KB
  int* counts    = (int*)(ws + off);   off += 64;  // counts[8] + nflag
  int* nflag     = counts + 8;
  int* worklist  = (int*)(ws + off);   off += (size_t)B_ROWS * 4;              // 32 KB
  int* bucket    = (int*)(ws + off);   off += (size_t)N_E * B_ROWS * 4;        // 256 KB
  float* pair_w  = (float*)(ws + off); off += (size_t)2 * B_ROWS * 4;
  int* pair_e    = (int*)(ws + off);   off += (size_t)2 * B_ROWS * 4;
  __bf16* h      = (__bf16*)(ws + off); off += (size_t)2 * B_ROWS * OUT_D * 2; // 32 MB

  hipMemsetAsync(counts, 0, 64, stream);
  convert_x_kernel<<<B_ROWS * D_INK / 4 / 256, 256, 0, stream>>>(
      (const float4*)x, (f16x4v*)x16h);
  transpose_split_kernel<<<dim3(D_H / 32, D_INK / 32, 1), dim3(32, 8), 0, stream>>>(
      gate_w1, w1th, D_INK, D_H);
  transpose_split_kernel<<<dim3(OUT_D / 32, D_INK / 32, N_E), dim3(32, 8), 0, stream>>>(
      We, wet, D_INK, OUT_D);
  gate_gemm_kernel<<<dim3(D_H / 128, B_ROWS / 128), 256, 0, stream>>>(
      x16h, w1th, gate_b1, g);
  score_kernel<<<B_ROWS / 4, 256, 0, stream>>>(
      g, gate_w2, gate_b2, scores, nflag, worklist);
  fixup_kernel<<<128, 256, 0, stream>>>(
      x, gate_w1, gate_b1, gate_w2, gate_b2, nflag, worklist, scores);
  select_kernel<<<B_ROWS / 256, 256, 0, stream>>>(
      scores, counts, bucket, pair_w, pair_e);
  expert_gemm_kernel<<<dim3(OUT_D / 128, B_ROWS / 128, N_E), 256, 0, stream>>>(
      x16h, wet, counts, bucket, h);
  ln_combine_kernel<<<B_ROWS, 256, 0, stream>>>(
      h, pair_w, pair_e, be, ln_g, ln_b, out);
}

// Round 6
// 393.574 us; speedup vs baseline: 1.2959x; 1.1408x over previous
//
#include <hip/hip_runtime.h>
#include <hip/hip_bf16.h>
#include <math.h>

#define B_ROWS 8192
#define D_INK  1024
#define D_H    512
#define N_E    8
#define OUT_D  1024
#define LN_EPS 1e-5f
#define GAP_TAU 3e-3f

typedef _Float16 f16x8 __attribute__((ext_vector_type(8)));
typedef _Float16 f16x4v __attribute__((ext_vector_type(4)));
typedef float    f32x4  __attribute__((ext_vector_type(4)));

__device__ __forceinline__ float gelu_exact(float x) {
  return 0.5f * x * (1.0f + erff(x * 0.707106781186547524f));
}
__device__ __forceinline__ float clamp_diag(float v) {
  return fminf(fmaxf(v, -1e15f), 1e15f);
}

// ---- x [8192][1024] fp32 -> fp16 ----
__global__ __launch_bounds__(256) void convert_x_kernel(
    const float4* __restrict__ x4, f16x4v* __restrict__ hi4) {
  int i = blockIdx.x * 256 + threadIdx.x;  // grid covers N/4 exactly
  float4 v = x4[i];
  f16x4v h;
  h[0] = (_Float16)v.x; h[1] = (_Float16)v.y;
  h[2] = (_Float16)v.z; h[3] = (_Float16)v.w;
  hi4[i] = h;
}

// ---- transpose fp32 [R][C] -> fp16 [C][R], z-batched ----
__global__ void transpose_split_kernel(const float* __restrict__ src,
                                       _Float16* __restrict__ hi,
                                       int R, int C) {
  __shared__ float tile[32][33];
  long base = (long)blockIdx.z * R * C;
  int c0 = blockIdx.x * 32, r0 = blockIdx.y * 32;
  int tx = threadIdx.x, ty = threadIdx.y;
#pragma unroll
  for (int i = ty; i < 32; i += 8)
    tile[i][tx] = src[base + (long)(r0 + i) * C + (c0 + tx)];
  __syncthreads();
#pragma unroll
  for (int i = ty; i < 32; i += 8)
    hi[base + (long)(c0 + i) * R + (r0 + tx)] = (_Float16)tile[tx][i];
}

// ---- gate GEMM, fp16 1-term: g = gelu(x@W1 + b1) fp32 out ----
// (score precision protected by GAP_TAU flag + fp64 fixup)
__global__ __launch_bounds__(256) void gate_gemm_kernel(
    const _Float16* __restrict__ xh, const _Float16* __restrict__ wh,
    const float* __restrict__ b1, float* __restrict__ g) {
  __shared__ __align__(16) unsigned short Ah[128 * 64];
  __shared__ __align__(16) unsigned short Bh[128 * 64];
  int tid = threadIdx.x, lane = tid & 63, wave = tid >> 6;
  int wm = wave >> 1, wn = wave & 1;
  int n0 = blockIdx.x * 128, m0 = blockIdx.y * 128;

  const char* pah[4]; const char* pbh[4];
#pragma unroll
  for (int i = 0; i < 4; ++i) {
    int f = i * 256 + tid;
    int rowt = f >> 3, seg = f & 7;
    pah[i] = (const char*)xh + (long)(m0 + rowt) * (D_INK * 2) + seg * 16;
    pbh[i] = (const char*)wh + (long)(n0 + rowt) * (D_INK * 2) + seg * 16;
  }
  f32x4 acc[4][4];
#pragma unroll
  for (int mi = 0; mi < 4; ++mi)
#pragma unroll
    for (int ni = 0; ni < 4; ++ni) acc[mi][ni] = (f32x4){0.f, 0.f, 0.f, 0.f};

  for (int k0 = 0; k0 < D_INK; k0 += 64) {
    f16x8 vah[4], vbh[4];
#pragma unroll
    for (int i = 0; i < 4; ++i) {
      vah[i] = *(const f16x8*)(pah[i] + (long)k0 * 2);
      vbh[i] = *(const f16x8*)(pbh[i] + (long)k0 * 2);
    }
    __syncthreads();
#pragma unroll
    for (int i = 0; i < 4; ++i) {
      *(f16x8*)((char*)Ah + (i * 256 + tid) * 16) = vah[i];
      *(f16x8*)((char*)Bh + (i * 256 + tid) * 16) = vbh[i];
    }
    __syncthreads();
#pragma unroll
    for (int ks = 0; ks < 2; ++ks) {
      int ko = (ks * 32 + ((lane >> 4) << 3)) * 2;
      f16x8 ah[4], bh[4];
#pragma unroll
      for (int mi = 0; mi < 4; ++mi)
        ah[mi] = *(const f16x8*)((const char*)Ah + (wm * 64 + mi * 16 + (lane & 15)) * 128 + ko);
#pragma unroll
      for (int ni = 0; ni < 4; ++ni)
        bh[ni] = *(const f16x8*)((const char*)Bh + (wn * 64 + ni * 16 + (lane & 15)) * 128 + ko);
#pragma unroll
      for (int mi = 0; mi < 4; ++mi)
#pragma unroll
        for (int ni = 0; ni < 4; ++ni)
          acc[mi][ni] = __builtin_amdgcn_mfma_f32_16x16x32_f16(ah[mi], bh[ni], acc[mi][ni], 0, 0, 0);
    }
  }
  int quad = lane >> 4, cl = lane & 15;
#pragma unroll
  for (int mi = 0; mi < 4; ++mi)
#pragma unroll
    for (int r = 0; r < 4; ++r) {
      int row = m0 + wm * 64 + mi * 16 + quad * 4 + r;
#pragma unroll
      for (int ni = 0; ni < 4; ++ni) {
        int col = n0 + wn * 64 + ni * 16 + cl;
        float v = clamp_diag(acc[mi][ni][r] + b1[col]);
        g[(long)row * D_H + col] = gelu_exact(v);
      }
    }
}

// ---- Phase A: scores (fp32) + flag close 2nd/3rd gaps. One wave per row ----
__global__ __launch_bounds__(256) void score_kernel(
    const float* __restrict__ g, const float* __restrict__ w2,
    const float* __restrict__ b2, float* __restrict__ scores,
    int* __restrict__ nflag, int* __restrict__ worklist) {
  int tid = threadIdx.x, lane = tid & 63, wave = tid >> 6;
  int b = blockIdx.x * 4 + wave;
  const float* grow = g + (long)b * D_H + lane * 8;
  float4 g0 = *(const float4*)grow;
  float4 g1 = *(const float4*)(grow + 4);
  float gv[8] = {g0.x, g0.y, g0.z, g0.w, g1.x, g1.y, g1.z, g1.w};
  float acc[8];
#pragma unroll
  for (int e = 0; e < 8; ++e) acc[e] = 0.f;
#pragma unroll
  for (int j = 0; j < 8; ++j) {
    const float* wrow = w2 + (lane * 8 + j) * N_E;
#pragma unroll
    for (int e = 0; e < 8; ++e) acc[e] += gv[j] * wrow[e];
  }
#pragma unroll
  for (int off = 32; off >= 1; off >>= 1)
#pragma unroll
    for (int e = 0; e < 8; ++e) acc[e] += __shfl_xor(acc[e], off, 64);
  if (lane == 0) {
    float s[8];
#pragma unroll
    for (int e = 0; e < 8; ++e) { s[e] = acc[e] + b2[e]; scores[b * N_E + e] = s[e]; }
    int i0 = 0;
#pragma unroll
    for (int e = 1; e < 8; ++e) if (s[e] > s[i0]) i0 = e;
    int i1 = (i0 == 0) ? 1 : 0;
#pragma unroll
    for (int e = 0; e < 8; ++e) if (e != i0 && s[e] > s[i1]) i1 = e;
    float s2 = -3e38f;
#pragma unroll
    for (int e = 0; e < 8; ++e) if (e != i0 && e != i1 && s[e] > s2) s2 = s[e];
    if (s[i1] - s2 < GAP_TAU) {
      int idx = atomicAdd(nflag, 1);
      worklist[idx] = b;
    }
  }
}

// ---- Phase B1: fp64 g for flagged rows. thread = one (row, col) pair ----
// Parallel axis = n*512 dot products; 4 accumulators break the FMA chain.
__global__ __launch_bounds__(256) void fixup_g_kernel(
    const float* __restrict__ x, const float* __restrict__ w1,
    const float* __restrict__ b1, const int* __restrict__ nflag,
    const int* __restrict__ worklist, double* __restrict__ g64) {
  int n = *nflag;
  int total = n * 2;  // tiles of 256 cols
  for (int t = blockIdx.x; t < total; t += gridDim.x) {
    int w = t >> 1, half = t & 1;
    int row = worklist[w];
    int col = half * 256 + threadIdx.x;
    const float* xr = x + (long)row * D_INK;
    double a0 = 0.0, a1 = 0.0, a2 = 0.0, a3 = 0.0;
    for (int k = 0; k < D_INK; k += 4) {
      a0 += (double)xr[k + 0] * (double)w1[(long)(k + 0) * D_H + col];
      a1 += (double)xr[k + 1] * (double)w1[(long)(k + 1) * D_H + col];
      a2 += (double)xr[k + 2] * (double)w1[(long)(k + 2) * D_H + col];
      a3 += (double)xr[k + 3] * (double)w1[(long)(k + 3) * D_H + col];
    }
    double s = ((a0 + a1) + (a2 + a3)) + (double)b1[col];
    g64[(long)w * D_H + col] = 0.5 * s * (1.0 + erf(s * 0.70710678118654752440));
  }
}

// ---- Phase B2: fp64 scores from g64, block per flagged row ----
__global__ __launch_bounds__(256) void fixup_score_kernel(
    const double* __restrict__ g64, const float* __restrict__ w2,
    const float* __restrict__ b2, const int* __restrict__ nflag,
    const int* __restrict__ worklist, float* __restrict__ scores) {
  __shared__ double p2[256];
  int n = *nflag;
  int tid = threadIdx.x;
  for (int w = blockIdx.x; w < n; w += gridDim.x) {
    int row = worklist[w];
    int e = tid & 7, seg = tid >> 3;  // 32 segments of 16
    double s = 0.0;
#pragma unroll
    for (int q = seg * 16; q < seg * 16 + 16; ++q)
      s += g64[(long)w * D_H + q] * (double)w2[q * N_E + e];
    p2[tid] = s;
    __syncthreads();
    if (tid < N_E) {
      double t = 0.0;
      for (int i = 0; i < 32; ++i) t += p2[i * 8 + tid];
      scores[row * N_E + tid] = (float)(t + (double)b2[tid]);
    }
    __syncthreads();
  }
}

// ---- Phase C: top-2 selection + softmax + bucket scatter (thread/row) ----
__global__ __launch_bounds__(256) void select_kernel(
    const float* __restrict__ scores, int* __restrict__ counts,
    int* __restrict__ bucket, float* __restrict__ pair_w,
    int* __restrict__ pair_e) {
  int b = blockIdx.x * 256 + threadIdx.x;
  float s[8];
#pragma unroll
  for (int e = 0; e < 8; ++e) s[e] = scores[b * N_E + e];
  int i0 = 0;
#pragma unroll
  for (int e = 1; e < 8; ++e) if (s[e] > s[i0]) i0 = e;
  int i1 = (i0 == 0) ? 1 : 0;
#pragma unroll
  for (int e = 0; e < 8; ++e) if (e != i0 && s[e] > s[i1]) i1 = e;
  float z = expf(s[i1] - s[i0]);  // <= 1
  float inv = 1.0f / (1.0f + z);
  int p0 = 2 * b, p1 = 2 * b + 1;
  pair_e[p0] = i0; pair_w[p0] = inv;
  pair_e[p1] = i1; pair_w[p1] = z * inv;
  int q0 = atomicAdd(&counts[i0], 1); bucket[i0 * B_ROWS + q0] = p0;
  int q1 = atomicAdd(&counts[i1], 1); bucket[i1 * B_ROWS + q1] = p1;
}

// ---- grouped expert GEMM (fp16): h[pair] = x[row] @ We[e], bf16 out ----
__global__ __launch_bounds__(256) void expert_gemm_kernel(
    const _Float16* __restrict__ xh, const _Float16* __restrict__ wet,
    const int* __restrict__ counts, const int* __restrict__ bucket,
    __bf16* __restrict__ h) {
  int nt = blockIdx.x, mt = blockIdx.y, e = blockIdx.z;
  int cnt = counts[e];
  if (mt * 128 >= cnt) return;
  __shared__ __align__(16) unsigned short As[128 * 64];
  __shared__ __align__(16) unsigned short Bs[128 * 64];
  __shared__ int dest_s[128];
  int tid = threadIdx.x, lane = tid & 63, wave = tid >> 6;
  int wm = wave >> 1, wn = wave & 1;
  int n0 = nt * 128;
  if (tid < 128) {
    int idx = mt * 128 + tid;
    dest_s[tid] = (idx < cnt) ? bucket[e * B_ROWS + idx] : 0;
  }
  __syncthreads();
  const char* xb = (const char*)xh;
  const char* wb = (const char*)wet + (long)e * (D_INK * OUT_D * 2);
  const char* aptr[4];
  const char* bptr[4];
#pragma unroll
  for (int i = 0; i < 4; ++i) {
    int f = i * 256 + tid;
    int rowt = f >> 3, seg = f & 7;
    int rowid = dest_s[rowt] >> 1;
    aptr[i] = xb + (long)rowid * (D_INK * 2) + seg * 16;
    bptr[i] = wb + (long)(n0 + rowt) * (D_INK * 2) + seg * 16;
  }
  f32x4 acc[4][4];
#pragma unroll
  for (int mi = 0; mi < 4; ++mi)
#pragma unroll
    for (int ni = 0; ni < 4; ++ni) acc[mi][ni] = (f32x4){0.f, 0.f, 0.f, 0.f};

  for (int k0 = 0; k0 < D_INK; k0 += 64) {
    f16x8 av[4], bv[4];
#pragma unroll
    for (int i = 0; i < 4; ++i) av[i] = *(const f16x8*)(aptr[i] + (long)k0 * 2);
#pragma unroll
    for (int i = 0; i < 4; ++i) bv[i] = *(const f16x8*)(bptr[i] + (long)k0 * 2);
    __syncthreads();
#pragma unroll
    for (int i = 0; i < 4; ++i)
      *(f16x8*)((char*)As + (i * 256 + tid) * 16) = av[i];
#pragma unroll
    for (int i = 0; i < 4; ++i)
      *(f16x8*)((char*)Bs + (i * 256 + tid) * 16) = bv[i];
    __syncthreads();
#pragma unroll
    for (int ks = 0; ks < 2; ++ks) {
      int ko = (ks * 32 + ((lane >> 4) << 3)) * 2;
      f16x8 af[4], bfr[4];
#pragma unroll
      for (int mi = 0; mi < 4; ++mi)
        af[mi] = *(const f16x8*)((const char*)As + (wm * 64 + mi * 16 + (lane & 15)) * 128 + ko);
#pragma unroll
      for (int ni = 0; ni < 4; ++ni)
        bfr[ni] = *(const f16x8*)((const char*)Bs + (wn * 64 + ni * 16 + (lane & 15)) * 128 + ko);
#pragma unroll
      for (int mi = 0; mi < 4; ++mi)
#pragma unroll
        for (int ni = 0; ni < 4; ++ni)
          acc[mi][ni] = __builtin_amdgcn_mfma_f32_16x16x32_f16(af[mi], bfr[ni], acc[mi][ni], 0, 0, 0);
    }
  }
  int quad = lane >> 4, cl = lane & 15;
#pragma unroll
  for (int mi = 0; mi < 4; ++mi)
#pragma unroll
    for (int r = 0; r < 4; ++r) {
      int row128 = wm * 64 + mi * 16 + quad * 4 + r;
      if (mt * 128 + row128 < cnt) {
        long dest = dest_s[row128];
        __bf16* hp = h + dest * OUT_D + n0 + wn * 64 + cl;
#pragma unroll
        for (int ni = 0; ni < 4; ++ni)
          hp[ni * 16] = (__bf16)clamp_diag(acc[mi][ni][r]);
      }
    }
}

// ---- LN(+be) -> GELU -> weighted combine -> fp32 out (block per row) ----
__global__ __launch_bounds__(256) void ln_combine_kernel(
    const __bf16* __restrict__ h, const float* __restrict__ pair_w,
    const int* __restrict__ pair_e, const float* __restrict__ be,
    const float* __restrict__ ln_g, const float* __restrict__ ln_b,
    float* __restrict__ out) {
  int b = blockIdx.x, tid = threadIdx.x;
  int lane = tid & 63, wave = tid >> 6;
  __shared__ float red[4][4];
  float hv[2][4];
  float stats[4];
  int ei[2]; float wi[2];
#pragma unroll
  for (int k = 0; k < 2; ++k) {
    int p = 2 * b + k;
    ei[k] = pair_e[p]; wi[k] = pair_w[p];
    const __bf16* hp = h + (long)p * OUT_D;
    const float* bep = be + ei[k] * OUT_D;
    float s = 0.f, sq = 0.f;
#pragma unroll
    for (int j = 0; j < 4; ++j) {
      int col = tid + j * 256;
      float v = (float)hp[col] + bep[col];
      hv[k][j] = v; s += v; sq += v * v;
    }
    stats[2 * k] = s; stats[2 * k + 1] = sq;
  }
#pragma unroll
  for (int off = 32; off >= 1; off >>= 1)
#pragma unroll
    for (int i = 0; i < 4; ++i) stats[i] += __shfl_xor(stats[i], off, 64);
  if (lane == 0) {
#pragma unroll
    for (int i = 0; i < 4; ++i) red[wave][i] = stats[i];
  }
  __syncthreads();
  float tot[4] = {0.f, 0.f, 0.f, 0.f};
#pragma unroll
  for (int w = 0; w < 4; ++w)
#pragma unroll
    for (int i = 0; i < 4; ++i) tot[i] += red[w][i];
  float outv[4] = {0.f, 0.f, 0.f, 0.f};
#pragma unroll
  for (int k = 0; k < 2; ++k) {
    float mean = tot[2 * k] * (1.0f / OUT_D);
    float var = tot[2 * k + 1] * (1.0f / OUT_D) - mean * mean;
    float rstd = rsqrtf(fmaxf(var, 0.f) + LN_EPS);
    const float* gp = ln_g + ei[k] * OUT_D;
    const float* bp = ln_b + ei[k] * OUT_D;
#pragma unroll
    for (int j = 0; j < 4; ++j) {
      int col = tid + j * 256;
      float t = (hv[k][j] - mean) * rstd * gp[col] + bp[col];
      outv[j] += wi[k] * gelu_exact(t);
    }
  }
#pragma unroll
  for (int j = 0; j < 4; ++j)
    out[(long)b * OUT_D + tid + j * 256] = outv[j];
}

extern "C" void kernel_launch(void* const* d_in, const int* in_sizes, int n_in,
                              void* d_out, int out_size, void* d_ws, size_t ws_size,
                              hipStream_t stream) {
  const float* x       = (const float*)d_in[0];
  const float* gate_w1 = (const float*)d_in[1];
  const float* gate_b1 = (const float*)d_in[2];
  const float* gate_w2 = (const float*)d_in[3];
  const float* gate_b2 = (const float*)d_in[4];
  const float* We      = (const float*)d_in[5];
  const float* be      = (const float*)d_in[6];
  const float* ln_g    = (const float*)d_in[7];
  const float* ln_b    = (const float*)d_in[8];
  float* out = (float*)d_out;  // reference output dtype is float32

  char* ws = (char*)d_ws;
  size_t off = 0;
  _Float16* x16h = (_Float16*)(ws + off); off += (size_t)B_ROWS * D_INK * 2;   // 16 MB
  _Float16* w1th = (_Float16*)(ws + off); off += (size_t)D_H * D_INK * 2;      // 1 MB
  _Float16* wet  = (_Float16*)(ws + off); off += (size_t)N_E * D_INK * OUT_D * 2; // 16 MB
  float* g       = (float*)(ws + off); off += (size_t)B_ROWS * D_H * 4;        // 16 MB
  float* scores  = (float*)(ws + off); off += (size_t)B_ROWS * N_E * 4;        // 256 KB
  int* counts    = (int*)(ws + off);   off += 64;  // counts[8] + nflag
  int* nflag     = counts + 8;
  int* worklist  = (int*)(ws + off);   off += (size_t)B_ROWS * 4;              // 32 KB
  int* bucket    = (int*)(ws + off);   off += (size_t)N_E * B_ROWS * 4;        // 256 KB
  float* pair_w  = (float*)(ws + off); off += (size_t)2 * B_ROWS * 4;
  int* pair_e    = (int*)(ws + off);   off += (size_t)2 * B_ROWS * 4;
  __bf16* h      = (__bf16*)(ws + off); off += (size_t)2 * B_ROWS * OUT_D * 2; // 32 MB
  // g64 aliases h: used only between fixup_g and fixup_score, both of which
  // complete before expert_gemm writes h. Worst case n=8192 -> 32 MB = |h|.
  double* g64    = (double*)h;

  hipMemsetAsync(counts, 0, 64, stream);
  convert_x_kernel<<<B_ROWS * D_INK / 4 / 256, 256, 0, stream>>>(
      (const float4*)x, (f16x4v*)x16h);
  transpose_split_kernel<<<dim3(D_H / 32, D_INK / 32, 1), dim3(32, 8), 0, stream>>>(
      gate_w1, w1th, D_INK, D_H);
  transpose_split_kernel<<<dim3(OUT_D / 32, D_INK / 32, N_E), dim3(32, 8), 0, stream>>>(
      We, wet, D_INK, OUT_D);
  gate_gemm_kernel<<<dim3(D_H / 128, B_ROWS / 128), 256, 0, stream>>>(
      x16h, w1th, gate_b1, g);
  score_kernel<<<B_ROWS / 4, 256, 0, stream>>>(
      g, gate_w2, gate_b2, scores, nflag, worklist);
  fixup_g_kernel<<<512, 256, 0, stream>>>(
      x, gate_w1, gate_b1, nflag, worklist, g64);
  fixup_score_kernel<<<128, 256, 0, stream>>>(
      g64, gate_w2, gate_b2, nflag, worklist, scores);
  select_kernel<<<B_ROWS / 256, 256, 0, stream>>>(
      scores, counts, bucket, pair_w, pair_e);
  expert_gemm_kernel<<<dim3(OUT_D / 128, B_ROWS / 128, N_E), 256, 0, stream>>>(
      x16h, wet, counts, bucket, h);
  ln_combine_kernel<<<B_ROWS, 256, 0, stream>>>(
      h, pair_w, pair_e, be, ln_g, ln_b, out);
}

// Round 7
// 384.941 us; speedup vs baseline: 1.3249x; 1.0224x over previous
//
#include <hip/hip_runtime.h>
#include <hip/hip_bf16.h>
#include <math.h>

#define B_ROWS 8192
#define D_INK  1024
#define D_H    512
#define N_E    8
#define OUT_D  1024
#define LN_EPS 1e-5f
#define GAP_TAU 3e-3f

typedef _Float16 f16x8 __attribute__((ext_vector_type(8)));
typedef _Float16 f16x4v __attribute__((ext_vector_type(4)));
typedef float    f32x4  __attribute__((ext_vector_type(4)));

#define GLOBAL_AS __attribute__((address_space(1)))
#define LDS_AS    __attribute__((address_space(3)))

// Async 16B global->LDS DMA. LDS dest is wave-uniform base + lane*16.
__device__ __forceinline__ void async16(const void* gptr, void* lptr) {
  __builtin_amdgcn_global_load_lds((const GLOBAL_AS unsigned int*)gptr,
                                   (LDS_AS unsigned int*)lptr, 16, 0, 0);
}

__device__ __forceinline__ float gelu_exact(float x) {
  return 0.5f * x * (1.0f + erff(x * 0.707106781186547524f));
}
__device__ __forceinline__ float clamp_diag(float v) {
  return fminf(fmaxf(v, -1e15f), 1e15f);
}

// ---- x [8192][1024] fp32 -> fp16 ----
__global__ __launch_bounds__(256) void convert_x_kernel(
    const float4* __restrict__ x4, f16x4v* __restrict__ hi4) {
  int i = blockIdx.x * 256 + threadIdx.x;  // grid covers N/4 exactly
  float4 v = x4[i];
  f16x4v h;
  h[0] = (_Float16)v.x; h[1] = (_Float16)v.y;
  h[2] = (_Float16)v.z; h[3] = (_Float16)v.w;
  hi4[i] = h;
}

// ---- transpose fp32 [R][C] -> fp16 [C][R], z-batched ----
__global__ void transpose_split_kernel(const float* __restrict__ src,
                                       _Float16* __restrict__ hi,
                                       int R, int C) {
  __shared__ float tile[32][33];
  long base = (long)blockIdx.z * R * C;
  int c0 = blockIdx.x * 32, r0 = blockIdx.y * 32;
  int tx = threadIdx.x, ty = threadIdx.y;
#pragma unroll
  for (int i = ty; i < 32; i += 8)
    tile[i][tx] = src[base + (long)(r0 + i) * C + (c0 + tx)];
  __syncthreads();
#pragma unroll
  for (int i = ty; i < 32; i += 8)
    hi[base + (long)(c0 + i) * R + (r0 + tx)] = (_Float16)tile[tx][i];
}

// LDS tile layout (both GEMMs): 128 rows x 8 segs of 16B, segment index
// XOR-swizzled by (row&7): data(row,seg) at row*128 + (seg^(row&7))*16.
// Staging fetches global segment slot^(row&7) into LDS slot `slot` so the
// DMA's rigid base+lane*16 mapping lands data swizzled. MFMA reads then are
// 2-way bank-aliased (free, m136) instead of 16-way.

// ---- gate GEMM, fp16 1-term: g = gelu(x@W1 + b1) fp32 out ----
// (score precision protected by GAP_TAU flag + fp64 fixup)
__global__ __launch_bounds__(256) void gate_gemm_kernel(
    const _Float16* __restrict__ xh, const _Float16* __restrict__ wh,
    const float* __restrict__ b1, float* __restrict__ g) {
  __shared__ __align__(16) unsigned short Ah[128 * 64];
  __shared__ __align__(16) unsigned short Bh[128 * 64];
  int tid = threadIdx.x, lane = tid & 63, wave = tid >> 6;
  int wm = wave >> 1, wn = wave & 1;
  int n0 = blockIdx.x * 128, m0 = blockIdx.y * 128;

  const char* pah[4]; const char* pbh[4];
#pragma unroll
  for (int i = 0; i < 4; ++i) {
    int f = i * 256 + tid;
    int rowt = f >> 3, slot = f & 7;
    int seg = slot ^ (rowt & 7);  // source-address swizzle
    pah[i] = (const char*)xh + (long)(m0 + rowt) * (D_INK * 2) + seg * 16;
    pbh[i] = (const char*)wh + (long)(n0 + rowt) * (D_INK * 2) + seg * 16;
  }
  f32x4 acc[4][4];
#pragma unroll
  for (int mi = 0; mi < 4; ++mi)
#pragma unroll
    for (int ni = 0; ni < 4; ++ni) acc[mi][ni] = (f32x4){0.f, 0.f, 0.f, 0.f};

  int cl = lane & 15, quad = lane >> 4;
  for (int k0 = 0; k0 < D_INK; k0 += 64) {
#pragma unroll
    for (int i = 0; i < 4; ++i) {
      async16(pah[i] + (long)k0 * 2, (char*)Ah + (i * 256 + wave * 64) * 16);
      async16(pbh[i] + (long)k0 * 2, (char*)Bh + (i * 256 + wave * 64) * 16);
    }
    __syncthreads();  // drains DMA (vmcnt) -> tile visible
#pragma unroll
    for (int ks = 0; ks < 2; ++ks) {
      f16x8 ah[4], bh[4];
#pragma unroll
      for (int mi = 0; mi < 4; ++mi) {
        int row = wm * 64 + mi * 16 + cl;
        ah[mi] = *(const f16x8*)((const char*)Ah + row * 128 +
                                 (((ks * 4 + quad) ^ (cl & 7)) * 16));
      }
#pragma unroll
      for (int ni = 0; ni < 4; ++ni) {
        int row = wn * 64 + ni * 16 + cl;
        bh[ni] = *(const f16x8*)((const char*)Bh + row * 128 +
                                 (((ks * 4 + quad) ^ (cl & 7)) * 16));
      }
#pragma unroll
      for (int mi = 0; mi < 4; ++mi)
#pragma unroll
        for (int ni = 0; ni < 4; ++ni)
          acc[mi][ni] = __builtin_amdgcn_mfma_f32_16x16x32_f16(ah[mi], bh[ni], acc[mi][ni], 0, 0, 0);
    }
    __syncthreads();  // tile consumed before next DMA overwrites
  }
#pragma unroll
  for (int mi = 0; mi < 4; ++mi)
#pragma unroll
    for (int r = 0; r < 4; ++r) {
      int row = m0 + wm * 64 + mi * 16 + quad * 4 + r;
#pragma unroll
      for (int ni = 0; ni < 4; ++ni) {
        int col = n0 + wn * 64 + ni * 16 + cl;
        float v = clamp_diag(acc[mi][ni][r] + b1[col]);
        g[(long)row * D_H + col] = gelu_exact(v);
      }
    }
}

// ---- Phase A: scores (fp32) + flag close 2nd/3rd gaps. One wave per row ----
__global__ __launch_bounds__(256) void score_kernel(
    const float* __restrict__ g, const float* __restrict__ w2,
    const float* __restrict__ b2, float* __restrict__ scores,
    int* __restrict__ nflag, int* __restrict__ worklist) {
  int tid = threadIdx.x, lane = tid & 63, wave = tid >> 6;
  int b = blockIdx.x * 4 + wave;
  const float* grow = g + (long)b * D_H + lane * 8;
  float4 g0 = *(const float4*)grow;
  float4 g1 = *(const float4*)(grow + 4);
  float gv[8] = {g0.x, g0.y, g0.z, g0.w, g1.x, g1.y, g1.z, g1.w};
  float acc[8];
#pragma unroll
  for (int e = 0; e < 8; ++e) acc[e] = 0.f;
#pragma unroll
  for (int j = 0; j < 8; ++j) {
    const float* wrow = w2 + (lane * 8 + j) * N_E;
#pragma unroll
    for (int e = 0; e < 8; ++e) acc[e] += gv[j] * wrow[e];
  }
#pragma unroll
  for (int off = 32; off >= 1; off >>= 1)
#pragma unroll
    for (int e = 0; e < 8; ++e) acc[e] += __shfl_xor(acc[e], off, 64);
  if (lane == 0) {
    float s[8];
#pragma unroll
    for (int e = 0; e < 8; ++e) { s[e] = acc[e] + b2[e]; scores[b * N_E + e] = s[e]; }
    int i0 = 0;
#pragma unroll
    for (int e = 1; e < 8; ++e) if (s[e] > s[i0]) i0 = e;
    int i1 = (i0 == 0) ? 1 : 0;
#pragma unroll
    for (int e = 0; e < 8; ++e) if (e != i0 && s[e] > s[i1]) i1 = e;
    float s2 = -3e38f;
#pragma unroll
    for (int e = 0; e < 8; ++e) if (e != i0 && e != i1 && s[e] > s2) s2 = s[e];
    if (s[i1] - s2 < GAP_TAU) {
      int idx = atomicAdd(nflag, 1);
      worklist[idx] = b;
    }
  }
}

// ---- Phase B1: fp64 g for flagged rows. thread = one (row, col) pair ----
__global__ __launch_bounds__(256) void fixup_g_kernel(
    const float* __restrict__ x, const float* __restrict__ w1,
    const float* __restrict__ b1, const int* __restrict__ nflag,
    const int* __restrict__ worklist, double* __restrict__ g64) {
  int n = *nflag;
  int total = n * 2;  // tiles of 256 cols
  for (int t = blockIdx.x; t < total; t += gridDim.x) {
    int w = t >> 1, half = t & 1;
    int row = worklist[w];
    int col = half * 256 + threadIdx.x;
    const float* xr = x + (long)row * D_INK;
    double a0 = 0.0, a1 = 0.0, a2 = 0.0, a3 = 0.0;
    for (int k = 0; k < D_INK; k += 4) {
      a0 += (double)xr[k + 0] * (double)w1[(long)(k + 0) * D_H + col];
      a1 += (double)xr[k + 1] * (double)w1[(long)(k + 1) * D_H + col];
      a2 += (double)xr[k + 2] * (double)w1[(long)(k + 2) * D_H + col];
      a3 += (double)xr[k + 3] * (double)w1[(long)(k + 3) * D_H + col];
    }
    double s = ((a0 + a1) + (a2 + a3)) + (double)b1[col];
    g64[(long)w * D_H + col] = 0.5 * s * (1.0 + erf(s * 0.70710678118654752440));
  }
}

// ---- Phase B2: fp64 scores from g64, block per flagged row ----
__global__ __launch_bounds__(256) void fixup_score_kernel(
    const double* __restrict__ g64, const float* __restrict__ w2,
    const float* __restrict__ b2, const int* __restrict__ nflag,
    const int* __restrict__ worklist, float* __restrict__ scores) {
  __shared__ double p2[256];
  int n = *nflag;
  int tid = threadIdx.x;
  for (int w = blockIdx.x; w < n; w += gridDim.x) {
    int row = worklist[w];
    int e = tid & 7, seg = tid >> 3;  // 32 segments of 16
    double s = 0.0;
#pragma unroll
    for (int q = seg * 16; q < seg * 16 + 16; ++q)
      s += g64[(long)w * D_H + q] * (double)w2[q * N_E + e];
    p2[tid] = s;
    __syncthreads();
    if (tid < N_E) {
      double t = 0.0;
      for (int i = 0; i < 32; ++i) t += p2[i * 8 + tid];
      scores[row * N_E + tid] = (float)(t + (double)b2[tid]);
    }
    __syncthreads();
  }
}

// ---- Phase C: top-2 selection + softmax + bucket scatter (thread/row) ----
__global__ __launch_bounds__(256) void select_kernel(
    const float* __restrict__ scores, int* __restrict__ counts,
    int* __restrict__ bucket, float* __restrict__ pair_w,
    int* __restrict__ pair_e) {
  int b = blockIdx.x * 256 + threadIdx.x;
  float s[8];
#pragma unroll
  for (int e = 0; e < 8; ++e) s[e] = scores[b * N_E + e];
  int i0 = 0;
#pragma unroll
  for (int e = 1; e < 8; ++e) if (s[e] > s[i0]) i0 = e;
  int i1 = (i0 == 0) ? 1 : 0;
#pragma unroll
  for (int e = 0; e < 8; ++e) if (e != i0 && s[e] > s[i1]) i1 = e;
  float z = expf(s[i1] - s[i0]);  // <= 1
  float inv = 1.0f / (1.0f + z);
  int p0 = 2 * b, p1 = 2 * b + 1;
  pair_e[p0] = i0; pair_w[p0] = inv;
  pair_e[p1] = i1; pair_w[p1] = z * inv;
  int q0 = atomicAdd(&counts[i0], 1); bucket[i0 * B_ROWS + q0] = p0;
  int q1 = atomicAdd(&counts[i1], 1); bucket[i1 * B_ROWS + q1] = p1;
}

// ---- grouped expert GEMM (fp16): h[pair] = x[row] @ We[e], bf16 out ----
__global__ __launch_bounds__(256) void expert_gemm_kernel(
    const _Float16* __restrict__ xh, const _Float16* __restrict__ wet,
    const int* __restrict__ counts, const int* __restrict__ bucket,
    __bf16* __restrict__ h) {
  int nt = blockIdx.x, mt = blockIdx.y, e = blockIdx.z;
  int cnt = counts[e];
  if (mt * 128 >= cnt) return;
  __shared__ __align__(16) unsigned short As[128 * 64];
  __shared__ __align__(16) unsigned short Bs[128 * 64];
  __shared__ int dest_s[128];
  int tid = threadIdx.x, lane = tid & 63, wave = tid >> 6;
  int wm = wave >> 1, wn = wave & 1;
  int n0 = nt * 128;
  if (tid < 128) {
    int idx = mt * 128 + tid;
    dest_s[tid] = (idx < cnt) ? bucket[e * B_ROWS + idx] : 0;
  }
  __syncthreads();
  const char* xb = (const char*)xh;
  const char* wb = (const char*)wet + (long)e * (D_INK * OUT_D * 2);
  const char* aptr[4];
  const char* bptr[4];
#pragma unroll
  for (int i = 0; i < 4; ++i) {
    int f = i * 256 + tid;
    int rowt = f >> 3, slot = f & 7;
    int seg = slot ^ (rowt & 7);  // source-address swizzle
    int rowid = dest_s[rowt] >> 1;
    aptr[i] = xb + (long)rowid * (D_INK * 2) + seg * 16;
    bptr[i] = wb + (long)(n0 + rowt) * (D_INK * 2) + seg * 16;
  }
  f32x4 acc[4][4];
#pragma unroll
  for (int mi = 0; mi < 4; ++mi)
#pragma unroll
    for (int ni = 0; ni < 4; ++ni) acc[mi][ni] = (f32x4){0.f, 0.f, 0.f, 0.f};

  int cl = lane & 15, quad = lane >> 4;
  for (int k0 = 0; k0 < D_INK; k0 += 64) {
#pragma unroll
    for (int i = 0; i < 4; ++i) {
      async16(aptr[i] + (long)k0 * 2, (char*)As + (i * 256 + wave * 64) * 16);
      async16(bptr[i] + (long)k0 * 2, (char*)Bs + (i * 256 + wave * 64) * 16);
    }
    __syncthreads();  // drains DMA (vmcnt) -> tile visible
#pragma unroll
    for (int ks = 0; ks < 2; ++ks) {
      f16x8 af[4], bfr[4];
#pragma unroll
      for (int mi = 0; mi < 4; ++mi) {
        int row = wm * 64 + mi * 16 + cl;
        af[mi] = *(const f16x8*)((const char*)As + row * 128 +
                                 (((ks * 4 + quad) ^ (cl & 7)) * 16));
      }
#pragma unroll
      for (int ni = 0; ni < 4; ++ni) {
        int row = wn * 64 + ni * 16 + cl;
        bfr[ni] = *(const f16x8*)((const char*)Bs + row * 128 +
                                  (((ks * 4 + quad) ^ (cl & 7)) * 16));
      }
#pragma unroll
      for (int mi = 0; mi < 4; ++mi)
#pragma unroll
        for (int ni = 0; ni < 4; ++ni)
          acc[mi][ni] = __builtin_amdgcn_mfma_f32_16x16x32_f16(af[mi], bfr[ni], acc[mi][ni], 0, 0, 0);
    }
    __syncthreads();  // tile consumed before next DMA overwrites
  }
#pragma unroll
  for (int mi = 0; mi < 4; ++mi)
#pragma unroll
    for (int r = 0; r < 4; ++r) {
      int row128 = wm * 64 + mi * 16 + quad * 4 + r;
      if (mt * 128 + row128 < cnt) {
        long dest = dest_s[row128];
        __bf16* hp = h + dest * OUT_D + n0 + wn * 64 + cl;
#pragma unroll
        for (int ni = 0; ni < 4; ++ni)
          hp[ni * 16] = (__bf16)clamp_diag(acc[mi][ni][r]);
      }
    }
}

// ---- LN(+be) -> GELU -> weighted combine -> fp32 out (block per row) ----
__global__ __launch_bounds__(256) void ln_combine_kernel(
    const __bf16* __restrict__ h, const float* __restrict__ pair_w,
    const int* __restrict__ pair_e, const float* __restrict__ be,
    const float* __restrict__ ln_g, const float* __restrict__ ln_b,
    float* __restrict__ out) {
  int b = blockIdx.x, tid = threadIdx.x;
  int lane = tid & 63, wave = tid >> 6;
  __shared__ float red[4][4];
  float hv[2][4];
  float stats[4];
  int ei[2]; float wi[2];
#pragma unroll
  for (int k = 0; k < 2; ++k) {
    int p = 2 * b + k;
    ei[k] = pair_e[p]; wi[k] = pair_w[p];
    const __bf16* hp = h + (long)p * OUT_D;
    const float* bep = be + ei[k] * OUT_D;
    float s = 0.f, sq = 0.f;
#pragma unroll
    for (int j = 0; j < 4; ++j) {
      int col = tid + j * 256;
      float v = (float)hp[col] + bep[col];
      hv[k][j] = v; s += v; sq += v * v;
    }
    stats[2 * k] = s; stats[2 * k + 1] = sq;
  }
#pragma unroll
  for (int off = 32; off >= 1; off >>= 1)
#pragma unroll
    for (int i = 0; i < 4; ++i) stats[i] += __shfl_xor(stats[i], off, 64);
  if (lane == 0) {
#pragma unroll
    for (int i = 0; i < 4; ++i) red[wave][i] = stats[i];
  }
  __syncthreads();
  float tot[4] = {0.f, 0.f, 0.f, 0.f};
#pragma unroll
  for (int w = 0; w < 4; ++w)
#pragma unroll
    for (int i = 0; i < 4; ++i) tot[i] += red[w][i];
  float outv[4] = {0.f, 0.f, 0.f, 0.f};
#pragma unroll
  for (int k = 0; k < 2; ++k) {
    float mean = tot[2 * k] * (1.0f / OUT_D);
    float var = tot[2 * k + 1] * (1.0f / OUT_D) - mean * mean;
    float rstd = rsqrtf(fmaxf(var, 0.f) + LN_EPS);
    const float* gp = ln_g + ei[k] * OUT_D;
    const float* bp = ln_b + ei[k] * OUT_D;
#pragma unroll
    for (int j = 0; j < 4; ++j) {
      int col = tid + j * 256;
      float t = (hv[k][j] - mean) * rstd * gp[col] + bp[col];
      outv[j] += wi[k] * gelu_exact(t);
    }
  }
#pragma unroll
  for (int j = 0; j < 4; ++j)
    out[(long)b * OUT_D + tid + j * 256] = outv[j];
}

extern "C" void kernel_launch(void* const* d_in, const int* in_sizes, int n_in,
                              void* d_out, int out_size, void* d_ws, size_t ws_size,
                              hipStream_t stream) {
  const float* x       = (const float*)d_in[0];
  const float* gate_w1 = (const float*)d_in[1];
  const float* gate_b1 = (const float*)d_in[2];
  const float* gate_w2 = (const float*)d_in[3];
  const float* gate_b2 = (const float*)d_in[4];
  const float* We      = (const float*)d_in[5];
  const float* be      = (const float*)d_in[6];
  const float* ln_g    = (const float*)d_in[7];
  const float* ln_b    = (const float*)d_in[8];
  float* out = (float*)d_out;  // reference output dtype is float32

  char* ws = (char*)d_ws;
  size_t off = 0;
  _Float16* x16h = (_Float16*)(ws + off); off += (size_t)B_ROWS * D_INK * 2;   // 16 MB
  _Float16* w1th = (_Float16*)(ws + off); off += (size_t)D_H * D_INK * 2;      // 1 MB
  _Float16* wet  = (_Float16*)(ws + off); off += (size_t)N_E * D_INK * OUT_D * 2; // 16 MB
  float* g       = (float*)(ws + off); off += (size_t)B_ROWS * D_H * 4;        // 16 MB
  float* scores  = (float*)(ws + off); off += (size_t)B_ROWS * N_E * 4;        // 256 KB
  int* counts    = (int*)(ws + off);   off += 64;  // counts[8] + nflag
  int* nflag     = counts + 8;
  int* worklist  = (int*)(ws + off);   off += (size_t)B_ROWS * 4;              // 32 KB
  int* bucket    = (int*)(ws + off);   off += (size_t)N_E * B_ROWS * 4;        // 256 KB
  float* pair_w  = (float*)(ws + off); off += (size_t)2 * B_ROWS * 4;
  int* pair_e    = (int*)(ws + off);   off += (size_t)2 * B_ROWS * 4;
  __bf16* h      = (__bf16*)(ws + off); off += (size_t)2 * B_ROWS * OUT_D * 2; // 32 MB
  // g64 aliases h: used only between fixup_g and fixup_score, both of which
  // complete before expert_gemm writes h. Worst case n=8192 -> 32 MB = |h|.
  double* g64    = (double*)h;

  hipMemsetAsync(counts, 0, 64, stream);
  convert_x_kernel<<<B_ROWS * D_INK / 4 / 256, 256, 0, stream>>>(
      (const float4*)x, (f16x4v*)x16h);
  transpose_split_kernel<<<dim3(D_H / 32, D_INK / 32, 1), dim3(32, 8), 0, stream>>>(
      gate_w1, w1th, D_INK, D_H);
  transpose_split_kernel<<<dim3(OUT_D / 32, D_INK / 32, N_E), dim3(32, 8), 0, stream>>>(
      We, wet, D_INK, OUT_D);
  gate_gemm_kernel<<<dim3(D_H / 128, B_ROWS / 128), 256, 0, stream>>>(
      x16h, w1th, gate_b1, g);
  score_kernel<<<B_ROWS / 4, 256, 0, stream>>>(
      g, gate_w2, gate_b2, scores, nflag, worklist);
  fixup_g_kernel<<<512, 256, 0, stream>>>(
      x, gate_w1, gate_b1, nflag, worklist, g64);
  fixup_score_kernel<<<128, 256, 0, stream>>>(
      g64, gate_w2, gate_b2, nflag, worklist, scores);
  select_kernel<<<B_ROWS / 256, 256, 0, stream>>>(
      scores, counts, bucket, pair_w, pair_e);
  expert_gemm_kernel<<<dim3(OUT_D / 128, B_ROWS / 128, N_E), 256, 0, stream>>>(
      x16h, wet, counts, bucket, h);
  ln_combine_kernel<<<B_ROWS, 256, 0, stream>>>(
      h, pair_w, pair_e, be, ln_g, ln_b, out);
}

// Round 8
// 315.130 us; speedup vs baseline: 1.6184x; 1.2215x over previous
//
#include <hip/hip_runtime.h>
#include <hip/hip_bf16.h>
#include <math.h>

#define B_ROWS 8192
#define D_INK  1024
#define D_H    512
#define N_E    8
#define OUT_D  1024
#define LN_EPS 1e-5f
#define GAP_TAU 3e-3f

typedef _Float16 f16x8 __attribute__((ext_vector_type(8)));
typedef _Float16 f16x4v __attribute__((ext_vector_type(4)));
typedef float    f32x4  __attribute__((ext_vector_type(4)));

#define GLOBAL_AS __attribute__((address_space(1)))
#define LDS_AS    __attribute__((address_space(3)))

// Async 16B global->LDS DMA. LDS dest is wave-uniform base + lane*16.
__device__ __forceinline__ void async16(const void* gptr, void* lptr) {
  __builtin_amdgcn_global_load_lds((const GLOBAL_AS unsigned int*)gptr,
                                   (LDS_AS unsigned int*)lptr, 16, 0, 0);
}

__device__ __forceinline__ float gelu_exact(float x) {
  return 0.5f * x * (1.0f + erff(x * 0.707106781186547524f));
}
__device__ __forceinline__ float clamp_diag(float v) {
  return fminf(fmaxf(v, -1e15f), 1e15f);
}

// ---- x [8192][1024] fp32 -> fp16 ----
__global__ __launch_bounds__(256) void convert_x_kernel(
    const float4* __restrict__ x4, f16x4v* __restrict__ hi4) {
  int i = blockIdx.x * 256 + threadIdx.x;  // grid covers N/4 exactly
  float4 v = x4[i];
  f16x4v h;
  h[0] = (_Float16)v.x; h[1] = (_Float16)v.y;
  h[2] = (_Float16)v.z; h[3] = (_Float16)v.w;
  hi4[i] = h;
}

// ---- transpose fp32 [R][C] -> fp16 [C][R], z-batched ----
__global__ void transpose_split_kernel(const float* __restrict__ src,
                                       _Float16* __restrict__ hi,
                                       int R, int C) {
  __shared__ float tile[32][33];
  long base = (long)blockIdx.z * R * C;
  int c0 = blockIdx.x * 32, r0 = blockIdx.y * 32;
  int tx = threadIdx.x, ty = threadIdx.y;
#pragma unroll
  for (int i = ty; i < 32; i += 8)
    tile[i][tx] = src[base + (long)(r0 + i) * C + (c0 + tx)];
  __syncthreads();
#pragma unroll
  for (int i = ty; i < 32; i += 8)
    hi[base + (long)(c0 + i) * R + (r0 + tx)] = (_Float16)tile[tx][i];
}

// LDS tile layout (both GEMMs): 128 rows x 8 segs of 16B, segment index
// XOR-swizzled by (row&7): data(row,seg) at row*128 + (seg^(row&7))*16.
// Staging fetches global segment slot^(row&7) into LDS slot `slot` so the
// DMA's rigid base+lane*16 mapping lands data swizzled. MFMA reads then are
// 2-way bank-aliased (free, m136) instead of 16-way.

// ---- gate GEMM, fp16 1-term: g = gelu(x@W1 + b1) fp32 out ----
// (score precision protected by GAP_TAU flag + fp64 fixup)
__global__ __launch_bounds__(256) void gate_gemm_kernel(
    const _Float16* __restrict__ xh, const _Float16* __restrict__ wh,
    const float* __restrict__ b1, float* __restrict__ g) {
  __shared__ __align__(16) unsigned short Ah[128 * 64];
  __shared__ __align__(16) unsigned short Bh[128 * 64];
  int tid = threadIdx.x, lane = tid & 63, wave = tid >> 6;
  int wm = wave >> 1, wn = wave & 1;
  int n0 = blockIdx.x * 128, m0 = blockIdx.y * 128;

  const char* pah[4]; const char* pbh[4];
#pragma unroll
  for (int i = 0; i < 4; ++i) {
    int f = i * 256 + tid;
    int rowt = f >> 3, slot = f & 7;
    int seg = slot ^ (rowt & 7);  // source-address swizzle
    pah[i] = (const char*)xh + (long)(m0 + rowt) * (D_INK * 2) + seg * 16;
    pbh[i] = (const char*)wh + (long)(n0 + rowt) * (D_INK * 2) + seg * 16;
  }
  f32x4 acc[4][4];
#pragma unroll
  for (int mi = 0; mi < 4; ++mi)
#pragma unroll
    for (int ni = 0; ni < 4; ++ni) acc[mi][ni] = (f32x4){0.f, 0.f, 0.f, 0.f};

  int cl = lane & 15, quad = lane >> 4;
  for (int k0 = 0; k0 < D_INK; k0 += 64) {
#pragma unroll
    for (int i = 0; i < 4; ++i) {
      async16(pah[i] + (long)k0 * 2, (char*)Ah + (i * 256 + wave * 64) * 16);
      async16(pbh[i] + (long)k0 * 2, (char*)Bh + (i * 256 + wave * 64) * 16);
    }
    __syncthreads();  // drains DMA (vmcnt) -> tile visible
#pragma unroll
    for (int ks = 0; ks < 2; ++ks) {
      f16x8 ah[4], bh[4];
#pragma unroll
      for (int mi = 0; mi < 4; ++mi) {
        int row = wm * 64 + mi * 16 + cl;
        ah[mi] = *(const f16x8*)((const char*)Ah + row * 128 +
                                 (((ks * 4 + quad) ^ (cl & 7)) * 16));
      }
#pragma unroll
      for (int ni = 0; ni < 4; ++ni) {
        int row = wn * 64 + ni * 16 + cl;
        bh[ni] = *(const f16x8*)((const char*)Bh + row * 128 +
                                 (((ks * 4 + quad) ^ (cl & 7)) * 16));
      }
#pragma unroll
      for (int mi = 0; mi < 4; ++mi)
#pragma unroll
        for (int ni = 0; ni < 4; ++ni)
          acc[mi][ni] = __builtin_amdgcn_mfma_f32_16x16x32_f16(ah[mi], bh[ni], acc[mi][ni], 0, 0, 0);
    }
    __syncthreads();  // tile consumed before next DMA overwrites
  }
#pragma unroll
  for (int mi = 0; mi < 4; ++mi)
#pragma unroll
    for (int r = 0; r < 4; ++r) {
      int row = m0 + wm * 64 + mi * 16 + quad * 4 + r;
#pragma unroll
      for (int ni = 0; ni < 4; ++ni) {
        int col = n0 + wn * 64 + ni * 16 + cl;
        float v = clamp_diag(acc[mi][ni][r] + b1[col]);
        g[(long)row * D_H + col] = gelu_exact(v);
      }
    }
}

// ---- Phase A: scores (fp32) + flag close 2nd/3rd gaps. One wave per row ----
__global__ __launch_bounds__(256) void score_kernel(
    const float* __restrict__ g, const float* __restrict__ w2,
    const float* __restrict__ b2, float* __restrict__ scores,
    int* __restrict__ nflag, int* __restrict__ worklist) {
  int tid = threadIdx.x, lane = tid & 63, wave = tid >> 6;
  int b = blockIdx.x * 4 + wave;
  const float* grow = g + (long)b * D_H + lane * 8;
  float4 g0 = *(const float4*)grow;
  float4 g1 = *(const float4*)(grow + 4);
  float gv[8] = {g0.x, g0.y, g0.z, g0.w, g1.x, g1.y, g1.z, g1.w};
  float acc[8];
#pragma unroll
  for (int e = 0; e < 8; ++e) acc[e] = 0.f;
#pragma unroll
  for (int j = 0; j < 8; ++j) {
    const float* wrow = w2 + (lane * 8 + j) * N_E;
#pragma unroll
    for (int e = 0; e < 8; ++e) acc[e] += gv[j] * wrow[e];
  }
#pragma unroll
  for (int off = 32; off >= 1; off >>= 1)
#pragma unroll
    for (int e = 0; e < 8; ++e) acc[e] += __shfl_xor(acc[e], off, 64);
  if (lane == 0) {
    float s[8];
#pragma unroll
    for (int e = 0; e < 8; ++e) { s[e] = acc[e] + b2[e]; scores[b * N_E + e] = s[e]; }
    int i0 = 0;
#pragma unroll
    for (int e = 1; e < 8; ++e) if (s[e] > s[i0]) i0 = e;
    int i1 = (i0 == 0) ? 1 : 0;
#pragma unroll
    for (int e = 0; e < 8; ++e) if (e != i0 && s[e] > s[i1]) i1 = e;
    float s2 = -3e38f;
#pragma unroll
    for (int e = 0; e < 8; ++e) if (e != i0 && e != i1 && s[e] > s2) s2 = s[e];
    if (s[i1] - s2 < GAP_TAU) {
      int idx = atomicAdd(nflag, 1);
      worklist[idx] = b;
    }
  }
}

// ---- Phase B1: fp64 g for flagged rows. thread = one (row, col) pair ----
__global__ __launch_bounds__(256) void fixup_g_kernel(
    const float* __restrict__ x, const float* __restrict__ w1,
    const float* __restrict__ b1, const int* __restrict__ nflag,
    const int* __restrict__ worklist, double* __restrict__ g64) {
  int n = *nflag;
  int total = n * 2;  // tiles of 256 cols
  for (int t = blockIdx.x; t < total; t += gridDim.x) {
    int w = t >> 1, half = t & 1;
    int row = worklist[w];
    int col = half * 256 + threadIdx.x;
    const float* xr = x + (long)row * D_INK;
    double a0 = 0.0, a1 = 0.0, a2 = 0.0, a3 = 0.0;
    for (int k = 0; k < D_INK; k += 4) {
      a0 += (double)xr[k + 0] * (double)w1[(long)(k + 0) * D_H + col];
      a1 += (double)xr[k + 1] * (double)w1[(long)(k + 1) * D_H + col];
      a2 += (double)xr[k + 2] * (double)w1[(long)(k + 2) * D_H + col];
      a3 += (double)xr[k + 3] * (double)w1[(long)(k + 3) * D_H + col];
    }
    double s = ((a0 + a1) + (a2 + a3)) + (double)b1[col];
    g64[(long)w * D_H + col] = 0.5 * s * (1.0 + erf(s * 0.70710678118654752440));
  }
}

// ---- Phase B2: fp64 scores from g64, block per flagged row ----
__global__ __launch_bounds__(256) void fixup_score_kernel(
    const double* __restrict__ g64, const float* __restrict__ w2,
    const float* __restrict__ b2, const int* __restrict__ nflag,
    const int* __restrict__ worklist, float* __restrict__ scores) {
  __shared__ double p2[256];
  int n = *nflag;
  int tid = threadIdx.x;
  for (int w = blockIdx.x; w < n; w += gridDim.x) {
    int row = worklist[w];
    int e = tid & 7, seg = tid >> 3;  // 32 segments of 16
    double s = 0.0;
#pragma unroll
    for (int q = seg * 16; q < seg * 16 + 16; ++q)
      s += g64[(long)w * D_H + q] * (double)w2[q * N_E + e];
    p2[tid] = s;
    __syncthreads();
    if (tid < N_E) {
      double t = 0.0;
      for (int i = 0; i < 32; ++i) t += p2[i * 8 + tid];
      scores[row * N_E + tid] = (float)(t + (double)b2[tid]);
    }
    __syncthreads();
  }
}

// ---- Phase C: top-2 + softmax + bucket scatter, hierarchical ranks ----
// Global atomics reduced 16384 -> 256 (8 per block) via LDS histogram;
// each thread's bucket slot = block_base[e] + LDS-atomic local rank.
__global__ __launch_bounds__(256) void select_kernel(
    const float* __restrict__ scores, int* __restrict__ counts,
    int* __restrict__ bucket, float* __restrict__ pair_w,
    int* __restrict__ pair_e) {
  __shared__ int lcnt[N_E];
  __shared__ int lbase[N_E];
  int tid = threadIdx.x;
  int b = blockIdx.x * 256 + tid;
  if (tid < N_E) lcnt[tid] = 0;
  __syncthreads();
  float s[8];
#pragma unroll
  for (int e = 0; e < 8; ++e) s[e] = scores[b * N_E + e];
  int i0 = 0;
#pragma unroll
  for (int e = 1; e < 8; ++e) if (s[e] > s[i0]) i0 = e;
  int i1 = (i0 == 0) ? 1 : 0;
#pragma unroll
  for (int e = 0; e < 8; ++e) if (e != i0 && s[e] > s[i1]) i1 = e;
  float z = expf(s[i1] - s[i0]);  // <= 1
  float inv = 1.0f / (1.0f + z);
  int r0 = atomicAdd(&lcnt[i0], 1);
  int r1 = atomicAdd(&lcnt[i1], 1);
  __syncthreads();
  if (tid < N_E) lbase[tid] = atomicAdd(&counts[tid], lcnt[tid]);
  __syncthreads();
  int p0 = 2 * b, p1 = 2 * b + 1;
  pair_e[p0] = i0; pair_w[p0] = inv;
  pair_e[p1] = i1; pair_w[p1] = z * inv;
  bucket[i0 * B_ROWS + lbase[i0] + r0] = p0;
  bucket[i1 * B_ROWS + lbase[i1] + r1] = p1;
}

// ---- grouped expert GEMM (fp16): h[pair] = x[row] @ We[e], bf16 out ----
__global__ __launch_bounds__(256) void expert_gemm_kernel(
    const _Float16* __restrict__ xh, const _Float16* __restrict__ wet,
    const int* __restrict__ counts, const int* __restrict__ bucket,
    __bf16* __restrict__ h) {
  int nt = blockIdx.x, mt = blockIdx.y, e = blockIdx.z;
  int cnt = counts[e];
  if (mt * 128 >= cnt) return;
  __shared__ __align__(16) unsigned short As[128 * 64];
  __shared__ __align__(16) unsigned short Bs[128 * 64];
  __shared__ int dest_s[128];
  int tid = threadIdx.x, lane = tid & 63, wave = tid >> 6;
  int wm = wave >> 1, wn = wave & 1;
  int n0 = nt * 128;
  if (tid < 128) {
    int idx = mt * 128 + tid;
    dest_s[tid] = (idx < cnt) ? bucket[e * B_ROWS + idx] : 0;
  }
  __syncthreads();
  const char* xb = (const char*)xh;
  const char* wb = (const char*)wet + (long)e * (D_INK * OUT_D * 2);
  const char* aptr[4];
  const char* bptr[4];
#pragma unroll
  for (int i = 0; i < 4; ++i) {
    int f = i * 256 + tid;
    int rowt = f >> 3, slot = f & 7;
    int seg = slot ^ (rowt & 7);  // source-address swizzle
    int rowid = dest_s[rowt] >> 1;
    aptr[i] = xb + (long)rowid * (D_INK * 2) + seg * 16;
    bptr[i] = wb + (long)(n0 + rowt) * (D_INK * 2) + seg * 16;
  }
  f32x4 acc[4][4];
#pragma unroll
  for (int mi = 0; mi < 4; ++mi)
#pragma unroll
    for (int ni = 0; ni < 4; ++ni) acc[mi][ni] = (f32x4){0.f, 0.f, 0.f, 0.f};

  int cl = lane & 15, quad = lane >> 4;
  for (int k0 = 0; k0 < D_INK; k0 += 64) {
#pragma unroll
    for (int i = 0; i < 4; ++i) {
      async16(aptr[i] + (long)k0 * 2, (char*)As + (i * 256 + wave * 64) * 16);
      async16(bptr[i] + (long)k0 * 2, (char*)Bs + (i * 256 + wave * 64) * 16);
    }
    __syncthreads();  // drains DMA (vmcnt) -> tile visible
#pragma unroll
    for (int ks = 0; ks < 2; ++ks) {
      f16x8 af[4], bfr[4];
#pragma unroll
      for (int mi = 0; mi < 4; ++mi) {
        int row = wm * 64 + mi * 16 + cl;
        af[mi] = *(const f16x8*)((const char*)As + row * 128 +
                                 (((ks * 4 + quad) ^ (cl & 7)) * 16));
      }
#pragma unroll
      for (int ni = 0; ni < 4; ++ni) {
        int row = wn * 64 + ni * 16 + cl;
        bfr[ni] = *(const f16x8*)((const char*)Bs + row * 128 +
                                  (((ks * 4 + quad) ^ (cl & 7)) * 16));
      }
#pragma unroll
      for (int mi = 0; mi < 4; ++mi)
#pragma unroll
        for (int ni = 0; ni < 4; ++ni)
          acc[mi][ni] = __builtin_amdgcn_mfma_f32_16x16x32_f16(af[mi], bfr[ni], acc[mi][ni], 0, 0, 0);
    }
    __syncthreads();  // tile consumed before next DMA overwrites
  }
#pragma unroll
  for (int mi = 0; mi < 4; ++mi)
#pragma unroll
    for (int r = 0; r < 4; ++r) {
      int row128 = wm * 64 + mi * 16 + quad * 4 + r;
      if (mt * 128 + row128 < cnt) {
        long dest = dest_s[row128];
        __bf16* hp = h + dest * OUT_D + n0 + wn * 64 + cl;
#pragma unroll
        for (int ni = 0; ni < 4; ++ni)
          hp[ni * 16] = (__bf16)clamp_diag(acc[mi][ni][r]);
      }
    }
}

// ---- LN(+be) -> GELU -> weighted combine -> fp32 out (block per row) ----
__global__ __launch_bounds__(256) void ln_combine_kernel(
    const __bf16* __restrict__ h, const float* __restrict__ pair_w,
    const int* __restrict__ pair_e, const float* __restrict__ be,
    const float* __restrict__ ln_g, const float* __restrict__ ln_b,
    float* __restrict__ out) {
  int b = blockIdx.x, tid = threadIdx.x;
  int lane = tid & 63, wave = tid >> 6;
  __shared__ float red[4][4];
  float hv[2][4];
  float stats[4];
  int ei[2]; float wi[2];
#pragma unroll
  for (int k = 0; k < 2; ++k) {
    int p = 2 * b + k;
    ei[k] = pair_e[p]; wi[k] = pair_w[p];
    const __bf16* hp = h + (long)p * OUT_D;
    const float* bep = be + ei[k] * OUT_D;
    float s = 0.f, sq = 0.f;
#pragma unroll
    for (int j = 0; j < 4; ++j) {
      int col = tid + j * 256;
      float v = (float)hp[col] + bep[col];
      hv[k][j] = v; s += v; sq += v * v;
    }
    stats[2 * k] = s; stats[2 * k + 1] = sq;
  }
#pragma unroll
  for (int off = 32; off >= 1; off >>= 1)
#pragma unroll
    for (int i = 0; i < 4; ++i) stats[i] += __shfl_xor(stats[i], off, 64);
  if (lane == 0) {
#pragma unroll
    for (int i = 0; i < 4; ++i) red[wave][i] = stats[i];
  }
  __syncthreads();
  float tot[4] = {0.f, 0.f, 0.f, 0.f};
#pragma unroll
  for (int w = 0; w < 4; ++w)
#pragma unroll
    for (int i = 0; i < 4; ++i) tot[i] += red[w][i];
  float outv[4] = {0.f, 0.f, 0.f, 0.f};
#pragma unroll
  for (int k = 0; k < 2; ++k) {
    float mean = tot[2 * k] * (1.0f / OUT_D);
    float var = tot[2 * k + 1] * (1.0f / OUT_D) - mean * mean;
    float rstd = rsqrtf(fmaxf(var, 0.f) + LN_EPS);
    const float* gp = ln_g + ei[k] * OUT_D;
    const float* bp = ln_b + ei[k] * OUT_D;
#pragma unroll
    for (int j = 0; j < 4; ++j) {
      int col = tid + j * 256;
      float t = (hv[k][j] - mean) * rstd * gp[col] + bp[col];
      outv[j] += wi[k] * gelu_exact(t);
    }
  }
#pragma unroll
  for (int j = 0; j < 4; ++j)
    out[(long)b * OUT_D + tid + j * 256] = outv[j];
}

extern "C" void kernel_launch(void* const* d_in, const int* in_sizes, int n_in,
                              void* d_out, int out_size, void* d_ws, size_t ws_size,
                              hipStream_t stream) {
  const float* x       = (const float*)d_in[0];
  const float* gate_w1 = (const float*)d_in[1];
  const float* gate_b1 = (const float*)d_in[2];
  const float* gate_w2 = (const float*)d_in[3];
  const float* gate_b2 = (const float*)d_in[4];
  const float* We      = (const float*)d_in[5];
  const float* be      = (const float*)d_in[6];
  const float* ln_g    = (const float*)d_in[7];
  const float* ln_b    = (const float*)d_in[8];
  float* out = (float*)d_out;  // reference output dtype is float32

  char* ws = (char*)d_ws;
  size_t off = 0;
  _Float16* x16h = (_Float16*)(ws + off); off += (size_t)B_ROWS * D_INK * 2;   // 16 MB
  _Float16* w1th = (_Float16*)(ws + off); off += (size_t)D_H * D_INK * 2;      // 1 MB
  _Float16* wet  = (_Float16*)(ws + off); off += (size_t)N_E * D_INK * OUT_D * 2; // 16 MB
  float* g       = (float*)(ws + off); off += (size_t)B_ROWS * D_H * 4;        // 16 MB
  float* scores  = (float*)(ws + off); off += (size_t)B_ROWS * N_E * 4;        // 256 KB
  int* counts    = (int*)(ws + off);   off += 64;  // counts[8] + nflag
  int* nflag     = counts + 8;
  int* worklist  = (int*)(ws + off);   off += (size_t)B_ROWS * 4;              // 32 KB
  int* bucket    = (int*)(ws + off);   off += (size_t)N_E * B_ROWS * 4;        // 256 KB
  float* pair_w  = (float*)(ws + off); off += (size_t)2 * B_ROWS * 4;
  int* pair_e    = (int*)(ws + off);   off += (size_t)2 * B_ROWS * 4;
  __bf16* h      = (__bf16*)(ws + off); off += (size_t)2 * B_ROWS * OUT_D * 2; // 32 MB
  // g64 aliases h: used only between fixup_g and fixup_score, both of which
  // complete before expert_gemm writes h. Worst case n=8192 -> 32 MB = |h|.
  double* g64    = (double*)h;

  hipMemsetAsync(counts, 0, 64, stream);
  convert_x_kernel<<<B_ROWS * D_INK / 4 / 256, 256, 0, stream>>>(
      (const float4*)x, (f16x4v*)x16h);
  transpose_split_kernel<<<dim3(D_H / 32, D_INK / 32, 1), dim3(32, 8), 0, stream>>>(
      gate_w1, w1th, D_INK, D_H);
  transpose_split_kernel<<<dim3(OUT_D / 32, D_INK / 32, N_E), dim3(32, 8), 0, stream>>>(
      We, wet, D_INK, OUT_D);
  gate_gemm_kernel<<<dim3(D_H / 128, B_ROWS / 128), 256, 0, stream>>>(
      x16h, w1th, gate_b1, g);
  score_kernel<<<B_ROWS / 4, 256, 0, stream>>>(
      g, gate_w2, gate_b2, scores, nflag, worklist);
  fixup_g_kernel<<<512, 256, 0, stream>>>(
      x, gate_w1, gate_b1, nflag, worklist, g64);
  fixup_score_kernel<<<128, 256, 0, stream>>>(
      g64, gate_w2, gate_b2, nflag, worklist, scores);
  select_kernel<<<B_ROWS / 256, 256, 0, stream>>>(
      scores, counts, bucket, pair_w, pair_e);
  expert_gemm_kernel<<<dim3(OUT_D / 128, B_ROWS / 128, N_E), 256, 0, stream>>>(
      x16h, wet, counts, bucket, h);
  ln_combine_kernel<<<B_ROWS, 256, 0, stream>>>(
      h, pair_w, pair_e, be, ln_g, ln_b, out);
}